// Round 8
// baseline (530.767 us; speedup 1.0000x reference)
//
#include <hip/hip_runtime.h>
#include <hip/hip_bf16.h>
#include <math.h>

#define NN 50000
#define EE 800000
#define DINK 512
#define DHK 128
#define CK 8
#define KIT 5
#define NBLKS 196  // ceil(NN/256)

typedef __attribute__((ext_vector_type(8))) short short8;
typedef __attribute__((ext_vector_type(4))) float f32x4;

__device__ __forceinline__ unsigned short f2bf(float f) {
    union { float f; unsigned int u; } v;
    v.f = f;
    unsigned int u = v.u;
    unsigned int r = (u + 0x7FFFu + ((u >> 16) & 1u)) >> 16;  // RNE
    return (unsigned short)r;
}
__device__ __forceinline__ float bfu2f(unsigned int lo16) {
    union { unsigned int u; float f; } v;
    v.u = lo16 << 16;
    return v.f;
}

// logH[i][j] = log_sigmoid(param[i][j] + param[j][i]), 8x8
__global__ __launch_bounds__(64) void logH_kernel(const float* __restrict__ param,
                                                  float* __restrict__ logH) {
    int t = threadIdx.x;
    int i = t >> 3, j = t & 7;
    float z = param[i * 8 + j] + param[j * 8 + i];
    logH[t] = fminf(z, 0.0f) - log1pf(expf(-fabsf(z)));
}

// W1 [512][128] fp32 -> W1t [128][512] bf16
__global__ __launch_bounds__(256) void w1t_kernel(const float* __restrict__ W1,
                                                  unsigned short* __restrict__ W1t) {
    int idx = blockIdx.x * 256 + threadIdx.x;  // 65536
    int n = idx >> 9;
    int k = idx & 511;
    W1t[idx] = f2bf(W1[(size_t)k * DHK + n]);
}

// MFMA MLP: logb0 = log_softmax(relu(x@W1+b1)@W2 + b2)
// block=256 (4 waves 2x2), tile 128 rows x 128 hidden, K-loop direct-from-global
// with 1-deep register prefetch.
__global__ __launch_bounds__(256) void mlp_mfma_kernel(
    const float* __restrict__ x, const unsigned short* __restrict__ W1t,
    const float* __restrict__ b1, const float* __restrict__ W2,
    const float* __restrict__ b2, float* __restrict__ logb0) {
    __shared__ unsigned short hs[128 * 136];
    __shared__ float W2s[128 * 8];
    __shared__ float b1s[128];
    __shared__ float b2s[8];

    const int tid = threadIdx.x;
    const int wave = tid >> 6;
    const int lane = tid & 63;
    const int q = lane >> 4;
    const int lm = lane & 15;
    const int wm = wave >> 1, wn = wave & 1;
    const int n0 = blockIdx.x * 128;

    if (tid < 128) b1s[tid] = b1[tid];
    if (tid < 8) b2s[tid] = b2[tid];
    {
        int i = tid * 4;
        *(float4*)&W2s[i] = *(const float4*)&W2[i];
    }
    __syncthreads();

    const float* xptr[4];
#pragma unroll
    for (int mt = 0; mt < 4; ++mt) {
        int r = n0 + wm * 64 + mt * 16 + lm;
        if (r > NN - 1) r = NN - 1;
        xptr[mt] = x + (size_t)r * DINK + q * 8;
    }
    const unsigned short* bptr[4];
#pragma unroll
    for (int nt = 0; nt < 4; ++nt) {
        int c = wn * 64 + nt * 16 + lm;
        bptr[nt] = W1t + (size_t)c * DINK + q * 8;
    }

    f32x4 acc[4][4];
#pragma unroll
    for (int mt = 0; mt < 4; ++mt)
#pragma unroll
        for (int nt = 0; nt < 4; ++nt) acc[mt][nt] = (f32x4){0.f, 0.f, 0.f, 0.f};

    float4 ar[4][2];
    short8 bc[4];
#pragma unroll
    for (int mt = 0; mt < 4; ++mt) {
        ar[mt][0] = *(const float4*)(xptr[mt]);
        ar[mt][1] = *(const float4*)(xptr[mt] + 4);
    }
#pragma unroll
    for (int nt = 0; nt < 4; ++nt) bc[nt] = *(const short8*)(bptr[nt]);

#pragma unroll
    for (int k0 = 32; k0 <= DINK; k0 += 32) {
        float4 ar2[4][2];
        short8 b2f[4];
        if (k0 < DINK) {
#pragma unroll
            for (int mt = 0; mt < 4; ++mt) {
                ar2[mt][0] = *(const float4*)(xptr[mt] + k0);
                ar2[mt][1] = *(const float4*)(xptr[mt] + k0 + 4);
            }
#pragma unroll
            for (int nt = 0; nt < 4; ++nt)
                b2f[nt] = *(const short8*)(bptr[nt] + k0);
        }
        short8 af[4];
#pragma unroll
        for (int mt = 0; mt < 4; ++mt) {
            union { short8 s; __hip_bfloat162 h[4]; } cv;
            cv.h[0] = __float22bfloat162_rn(make_float2(ar[mt][0].x, ar[mt][0].y));
            cv.h[1] = __float22bfloat162_rn(make_float2(ar[mt][0].z, ar[mt][0].w));
            cv.h[2] = __float22bfloat162_rn(make_float2(ar[mt][1].x, ar[mt][1].y));
            cv.h[3] = __float22bfloat162_rn(make_float2(ar[mt][1].z, ar[mt][1].w));
            af[mt] = cv.s;
        }
#pragma unroll
        for (int mt = 0; mt < 4; ++mt)
#pragma unroll
            for (int nt = 0; nt < 4; ++nt)
                acc[mt][nt] = __builtin_amdgcn_mfma_f32_16x16x32_bf16(
                    af[mt], bc[nt], acc[mt][nt], 0, 0, 0);
        if (k0 < DINK) {
#pragma unroll
            for (int mt = 0; mt < 4; ++mt) {
                ar[mt][0] = ar2[mt][0];
                ar[mt][1] = ar2[mt][1];
            }
#pragma unroll
            for (int nt = 0; nt < 4; ++nt) bc[nt] = b2f[nt];
        }
    }

#pragma unroll
    for (int nt = 0; nt < 4; ++nt) {
        int j = wn * 64 + nt * 16 + lm;
        float bj = b1s[j];
#pragma unroll
        for (int mt = 0; mt < 4; ++mt) {
            int rbase = wm * 64 + mt * 16 + q * 4;
#pragma unroll
            for (int r = 0; r < 4; ++r) {
                float h = fmaxf(acc[mt][nt][r] + bj, 0.0f);
                hs[(rbase + r) * 136 + j] = f2bf(h);
            }
        }
    }
    __syncthreads();

    int row = tid >> 1;
    int half = tid & 1;
    const unsigned short* hp = &hs[row * 136 + half * 64];
    float p[8] = {0.f, 0.f, 0.f, 0.f, 0.f, 0.f, 0.f, 0.f};
#pragma unroll
    for (int ch = 0; ch < 8; ++ch) {
        uint4 c4 = *(const uint4*)(hp + ch * 8);
        unsigned int uu[4] = {c4.x, c4.y, c4.z, c4.w};
#pragma unroll
        for (int p2 = 0; p2 < 4; ++p2) {
            float h0 = bfu2f(uu[p2] & 0xFFFFu);
            float h1 = bfu2f(uu[p2] >> 16);
            int j = half * 64 + ch * 8 + p2 * 2;
            const float* w0 = &W2s[j * 8];
            const float* w1 = &W2s[(j + 1) * 8];
#pragma unroll
            for (int c = 0; c < 8; ++c) p[c] = fmaf(h0, w0[c], p[c]);
#pragma unroll
            for (int c = 0; c < 8; ++c) p[c] = fmaf(h1, w1[c], p[c]);
        }
    }
#pragma unroll
    for (int c = 0; c < 8; ++c) p[c] += __shfl_xor(p[c], 1, 64);
    int grow = n0 + row;
    if (half == 0 && grow < NN) {
        float v[8];
        float mx = -1e30f;
#pragma unroll
        for (int c = 0; c < 8; ++c) {
            v[c] = p[c] + b2s[c];
            mx = fmaxf(mx, v[c]);
        }
        float s = 0.0f;
#pragma unroll
        for (int c = 0; c < 8; ++c) s += expf(v[c] - mx);
        float ln = mx + logf(s);
        float4* p0 = (float4*)&logb0[(size_t)grow * 8];
        p0[0] = make_float4(v[0] - ln, v[1] - ln, v[2] - ln, v[3] - ln);
        p0[1] = make_float4(v[4] - ln, v[5] - ln, v[6] - ln, v[7] - ln);
    }
}

// ---------------- CSR setup kernels ----------------

__global__ __launch_bounds__(256) void deg_kernel(const int* __restrict__ dst,
                                                  int* __restrict__ cnt) {
    int e = blockIdx.x * 256 + threadIdx.x;
    if (e < EE) atomicAdd(&cnt[dst[e]], 1);
}

__global__ __launch_bounds__(256) void scan_partial_kernel(
    const int* __restrict__ cnt, int* __restrict__ partial) {
    __shared__ int sd[256];
    int t = threadIdx.x;
    int i = blockIdx.x * 256 + t;
    sd[t] = (i < NN) ? cnt[i] : 0;
    __syncthreads();
#pragma unroll
    for (int s = 128; s > 0; s >>= 1) {
        if (t < s) sd[t] += sd[t + s];
        __syncthreads();
    }
    if (t == 0) partial[blockIdx.x] = sd[0];
}

__global__ __launch_bounds__(256) void scan_tops_kernel(
    const int* __restrict__ partial, int* __restrict__ tops) {
    __shared__ int sd[256];
    int t = threadIdx.x;
    sd[t] = (t < NBLKS) ? partial[t] : 0;
    __syncthreads();
#pragma unroll
    for (int s = 1; s < 256; s <<= 1) {
        int a = sd[t];
        int b = (t >= s) ? sd[t - s] : 0;
        __syncthreads();
        sd[t] = a + b;
        __syncthreads();
    }
    if (t < NBLKS) tops[t] = (t > 0) ? sd[t - 1] : 0;
}

__global__ __launch_bounds__(256) void scan_write_kernel(
    const int* __restrict__ cnt, const int* __restrict__ tops,
    int* __restrict__ off) {
    __shared__ int sd[256];
    int t = threadIdx.x;
    int i = blockIdx.x * 256 + t;
    int v = (i < NN) ? cnt[i] : 0;
    sd[t] = v;
    __syncthreads();
#pragma unroll
    for (int s = 1; s < 256; s <<= 1) {
        int a = sd[t];
        int b = (t >= s) ? sd[t - s] : 0;
        __syncthreads();
        sd[t] = a + b;
        __syncthreads();
    }
    if (i < NN) off[i] = tops[blockIdx.x] + sd[t] - v;
    if (i == NN - 1) off[NN] = EE;
}

__global__ __launch_bounds__(256) void pos_kernel(
    const int* __restrict__ src, const int* __restrict__ dst,
    const float* __restrict__ ew, const int* __restrict__ off,
    int* __restrict__ cnt, int* __restrict__ pos,
    int2* __restrict__ perm_sw) {
    int e = blockIdx.x * 256 + threadIdx.x;
    if (e >= EE) return;
    int d = dst[e];
    int p = off[d] + atomicAdd(&cnt[d], 1);
    pos[e] = p;
    int2 sw;
    sw.x = src[e];
    sw.y = __float_as_int(ew[e]);
    perm_sw[p] = sw;
}

__global__ __launch_bounds__(256) void rvpos_kernel(const int* __restrict__ rv,
                                                    const int* __restrict__ pos,
                                                    int* __restrict__ perm_rvp) {
    int e = blockIdx.x * 256 + threadIdx.x;
    if (e >= EE) return;
    perm_rvp[pos[e]] = pos[rv[e]];
}

// xin[p] = logb0[perm_src[p]]; also unpack perm_w
__global__ __launch_bounds__(256) void init_xin_kernel(
    const int2* __restrict__ perm_sw, const float* __restrict__ logb0,
    float* __restrict__ xin, float* __restrict__ perm_w) {
    int p = blockIdx.x * 256 + threadIdx.x;
    if (p >= EE) return;
    int2 sw = perm_sw[p];
    perm_w[p] = __int_as_float(sw.y);
    const float4* pb = (const float4*)&logb0[(size_t)sw.x * 8];
    float4 a = pb[0], b = pb[1];
    float4* po = (float4*)&xin[(size_t)p * 8];
    po[0] = a;
    po[1] = b;
}

// ---------------- fused BP iteration (node-centric, no msg buffer) ----------
// 8 threads per node (thread = output channel c). Per-edge messages are
// deliberately UNNORMALIZED: the per-edge normalizer is channel-uniform, so
// it cancels in the node normalize and in the xin = v - msg chain.
// Pass 1: aggregate raw messages; normalize belief. Pass 2: recompute message
// (xin L1-hot, exp is cheap) and scatter next-iter edge input.
__global__ __launch_bounds__(256) void bp_iter_kernel(
    const float* __restrict__ logb0, const int* __restrict__ off,
    const float* __restrict__ perm_w, const int* __restrict__ perm_rvp,
    const float* __restrict__ logH, const float* __restrict__ xin,
    float* __restrict__ xout, float* __restrict__ out, int write_out) {
    int t = blockIdx.x * 256 + threadIdx.x;
    int n = t >> 3;
    int c = t & 7;
    if (n >= NN) return;

    float lHc[8];
#pragma unroll
    for (int c1 = 0; c1 < 8; ++c1) lHc[c1] = logH[c1 * 8 + c];

    int j0 = off[n], j1 = off[n + 1];
    float a = logb0[(size_t)n * 8 + c];

    for (int j = j0; j < j1; ++j) {
        float w = perm_w[j];
        const float4* pb = (const float4*)&xin[(size_t)j * 8];
        float4 v0 = pb[0], v1 = pb[1];
        float xj[8] = {v0.x, v0.y, v0.z, v0.w, v1.x, v1.y, v1.z, v1.w};
        float M = xj[0];
#pragma unroll
        for (int k = 1; k < 8; ++k) M = fmaxf(M, xj[k]);
        float ssum = 0.0f;
#pragma unroll
        for (int c1 = 0; c1 < 8; ++c1)
            ssum += __expf(fmaf(w, lHc[c1], xj[c1] - M));
        a += M + __logf(ssum);
    }

    // normalize belief across the 8 channels (8-thread group)
    float mx = a;
#pragma unroll
    for (int s = 1; s < 8; s <<= 1) mx = fmaxf(mx, __shfl_xor(mx, s, 8));
    float ex = __expf(a - mx);
    float sum = ex;
#pragma unroll
    for (int s = 1; s < 8; s <<= 1) sum += __shfl_xor(sum, s, 8);
    float v = a - (mx + __logf(sum));

    if (write_out) {
        out[(size_t)n * 8 + c] = v;
        return;
    }
    // pass 2: recompute messages, scatter next-iter inputs
    for (int j = j0; j < j1; ++j) {
        float w = perm_w[j];
        const float4* pb = (const float4*)&xin[(size_t)j * 8];
        float4 v0 = pb[0], v1 = pb[1];
        float xj[8] = {v0.x, v0.y, v0.z, v0.w, v1.x, v1.y, v1.z, v1.w};
        float M = xj[0];
#pragma unroll
        for (int k = 1; k < 8; ++k) M = fmaxf(M, xj[k]);
        float ssum = 0.0f;
#pragma unroll
        for (int c1 = 0; c1 < 8; ++c1)
            ssum += __expf(fmaf(w, lHc[c1], xj[c1] - M));
        float mg = M + __logf(ssum);
        int r = perm_rvp[j];
        xout[(size_t)r * 8 + c] = v - mg;
    }
}

extern "C" void kernel_launch(void* const* d_in, const int* in_sizes, int n_in,
                              void* d_out, int out_size, void* d_ws, size_t ws_size,
                              hipStream_t stream) {
    const float* x = (const float*)d_in[0];
    const int* ei = (const int*)d_in[1];
    const float* ew = (const float*)d_in[2];
    const int* rv = (const int*)d_in[3];
    const float* W1 = (const float*)d_in[4];
    const float* b1 = (const float*)d_in[5];
    const float* W2 = (const float*)d_in[6];
    const float* b2 = (const float*)d_in[7];
    const float* param = (const float*)d_in[8];
    float* out = (float*)d_out;

    const int* src = ei;
    const int* dst = ei + EE;

    float* wsf = (float*)d_ws;
    float* logH = wsf;                          // 64
    float* logb0 = logH + 64;                   // 400000
    float* xinA = logb0 + (size_t)NN * 8;       // 6.4M
    float* xinB = xinA + (size_t)EE * 8;        // 6.4M
    float* perm_w = xinB + (size_t)EE * 8;      // 800000
    int* off = (int*)(perm_w + EE);             // 50001
    int2* perm_sw = (int2*)(off + (NN + 1));    // 800000 int2
    int* perm_rvp = (int*)(perm_sw + EE);       // 800000
    unsigned short* W1t = (unsigned short*)(perm_rvp + EE);  // 65536 bf16
    // setup-only scratch aliases xinA (first written by init_xin after setup)
    int* pos = (int*)xinA;                      // 800000
    int* cnt = pos + EE;                        // 50000
    int* partial = cnt + NN;                    // 196
    int* tops = partial + NBLKS;                // 196

    logH_kernel<<<1, 64, 0, stream>>>(param, logH);
    w1t_kernel<<<256, 256, 0, stream>>>(W1, W1t);
    mlp_mfma_kernel<<<(NN + 127) / 128, 256, 0, stream>>>(x, W1t, b1, W2, b2,
                                                          logb0);

    const int EB = (EE + 255) / 256;

    hipMemsetAsync(cnt, 0, (size_t)NN * sizeof(int), stream);
    deg_kernel<<<EB, 256, 0, stream>>>(dst, cnt);
    scan_partial_kernel<<<NBLKS, 256, 0, stream>>>(cnt, partial);
    scan_tops_kernel<<<1, 256, 0, stream>>>(partial, tops);
    scan_write_kernel<<<NBLKS, 256, 0, stream>>>(cnt, tops, off);
    hipMemsetAsync(cnt, 0, (size_t)NN * sizeof(int), stream);
    pos_kernel<<<EB, 256, 0, stream>>>(src, dst, ew, off, cnt, pos, perm_sw);
    rvpos_kernel<<<EB, 256, 0, stream>>>(rv, pos, perm_rvp);
    init_xin_kernel<<<EB, 256, 0, stream>>>(perm_sw, logb0, xinA, perm_w);

    const int NB8 = (NN * 8 + 255) / 256;
    float* cur = xinA;
    float* nxt = xinB;
    for (int it = 0; it < KIT; ++it) {
        bp_iter_kernel<<<NB8, 256, 0, stream>>>(
            logb0, off, perm_w, perm_rvp, logH, cur, nxt, out,
            it == KIT - 1 ? 1 : 0);
        float* tmp = cur; cur = nxt; nxt = tmp;
    }
}

// Round 9
// 525.571 us; speedup vs baseline: 1.0099x; 1.0099x over previous
//
#include <hip/hip_runtime.h>
#include <hip/hip_bf16.h>
#include <math.h>

#define NN 50000
#define EE 800000
#define DINK 512
#define DHK 128
#define CK 8
#define KIT 5
#define NBLKS 196  // ceil(NN/256)

typedef __attribute__((ext_vector_type(8))) short short8;
typedef __attribute__((ext_vector_type(4))) float f32x4;

__device__ __forceinline__ unsigned short f2bf(float f) {
    union { float f; unsigned int u; } v;
    v.f = f;
    unsigned int u = v.u;
    unsigned int r = (u + 0x7FFFu + ((u >> 16) & 1u)) >> 16;  // RNE
    return (unsigned short)r;
}
__device__ __forceinline__ float bfu2f(unsigned int lo16) {
    union { unsigned int u; float f; } v;
    v.u = lo16 << 16;
    return v.f;
}

// logH[i][j] = log_sigmoid(param[i][j] + param[j][i]), 8x8
__global__ __launch_bounds__(64) void logH_kernel(const float* __restrict__ param,
                                                  float* __restrict__ logH) {
    int t = threadIdx.x;
    int i = t >> 3, j = t & 7;
    float z = param[i * 8 + j] + param[j * 8 + i];
    logH[t] = fminf(z, 0.0f) - log1pf(expf(-fabsf(z)));
}

// W1 [512][128] fp32 -> W1t [128][512] bf16
__global__ __launch_bounds__(256) void w1t_kernel(const float* __restrict__ W1,
                                                  unsigned short* __restrict__ W1t) {
    int idx = blockIdx.x * 256 + threadIdx.x;  // 65536
    int n = idx >> 9;
    int k = idx & 511;
    W1t[idx] = f2bf(W1[(size_t)k * DHK + n]);
}

// MFMA MLP: logb0 = log_softmax(relu(x@W1+b1)@W2 + b2)
// block=512 (8 waves, 2x4 wave grid), tile 128 rows x 128 hidden.
// K-loop direct-from-global with 1-deep register prefetch. 512 threads/block
// doubles resident waves (grid is the occupancy limiter at 391 blocks).
__global__ __launch_bounds__(512) void mlp_mfma_kernel(
    const float* __restrict__ x, const unsigned short* __restrict__ W1t,
    const float* __restrict__ b1, const float* __restrict__ W2,
    const float* __restrict__ b2, float* __restrict__ logb0) {
    __shared__ unsigned short hs[128 * 136];
    __shared__ float W2s[128 * 8];
    __shared__ float b1s[128];
    __shared__ float b2s[8];

    const int tid = threadIdx.x;
    const int wave = tid >> 6;
    const int lane = tid & 63;
    const int q = lane >> 4;
    const int lm = lane & 15;
    const int wm = wave >> 2, wn = wave & 3;  // 2 wave-rows x 4 wave-cols
    const int n0 = blockIdx.x * 128;

    if (tid < 128) b1s[tid] = b1[tid];
    if (tid < 8) b2s[tid] = b2[tid];
    if (tid < 256) {
        int i = tid * 4;
        *(float4*)&W2s[i] = *(const float4*)&W2[i];
    }
    __syncthreads();

    const float* xptr[4];
#pragma unroll
    for (int mt = 0; mt < 4; ++mt) {
        int r = n0 + wm * 64 + mt * 16 + lm;
        if (r > NN - 1) r = NN - 1;
        xptr[mt] = x + (size_t)r * DINK + q * 8;
    }
    const unsigned short* bptr[2];
#pragma unroll
    for (int nt = 0; nt < 2; ++nt) {
        int c = wn * 32 + nt * 16 + lm;
        bptr[nt] = W1t + (size_t)c * DINK + q * 8;
    }

    f32x4 acc[4][2];
#pragma unroll
    for (int mt = 0; mt < 4; ++mt)
#pragma unroll
        for (int nt = 0; nt < 2; ++nt) acc[mt][nt] = (f32x4){0.f, 0.f, 0.f, 0.f};

    // 1-deep register prefetch
    float4 ar[4][2];
    short8 bc[2];
#pragma unroll
    for (int mt = 0; mt < 4; ++mt) {
        ar[mt][0] = *(const float4*)(xptr[mt]);
        ar[mt][1] = *(const float4*)(xptr[mt] + 4);
    }
#pragma unroll
    for (int nt = 0; nt < 2; ++nt) bc[nt] = *(const short8*)(bptr[nt]);

#pragma unroll
    for (int k0 = 32; k0 <= DINK; k0 += 32) {
        float4 ar2[4][2];
        short8 b2f[2];
        if (k0 < DINK) {
#pragma unroll
            for (int mt = 0; mt < 4; ++mt) {
                ar2[mt][0] = *(const float4*)(xptr[mt] + k0);
                ar2[mt][1] = *(const float4*)(xptr[mt] + k0 + 4);
            }
#pragma unroll
            for (int nt = 0; nt < 2; ++nt)
                b2f[nt] = *(const short8*)(bptr[nt] + k0);
        }
        short8 af[4];
#pragma unroll
        for (int mt = 0; mt < 4; ++mt) {
            union { short8 s; __hip_bfloat162 h[4]; } cv;
            cv.h[0] = __float22bfloat162_rn(make_float2(ar[mt][0].x, ar[mt][0].y));
            cv.h[1] = __float22bfloat162_rn(make_float2(ar[mt][0].z, ar[mt][0].w));
            cv.h[2] = __float22bfloat162_rn(make_float2(ar[mt][1].x, ar[mt][1].y));
            cv.h[3] = __float22bfloat162_rn(make_float2(ar[mt][1].z, ar[mt][1].w));
            af[mt] = cv.s;
        }
#pragma unroll
        for (int mt = 0; mt < 4; ++mt)
#pragma unroll
            for (int nt = 0; nt < 2; ++nt)
                acc[mt][nt] = __builtin_amdgcn_mfma_f32_16x16x32_bf16(
                    af[mt], bc[nt], acc[mt][nt], 0, 0, 0);
        if (k0 < DINK) {
#pragma unroll
            for (int mt = 0; mt < 4; ++mt) {
                ar[mt][0] = ar2[mt][0];
                ar[mt][1] = ar2[mt][1];
            }
#pragma unroll
            for (int nt = 0; nt < 2; ++nt) bc[nt] = b2f[nt];
        }
    }

    // bias + relu -> hs bf16. C/D layout: col=lane&15, row=(lane>>4)*4+reg
#pragma unroll
    for (int nt = 0; nt < 2; ++nt) {
        int j = wn * 32 + nt * 16 + lm;
        float bj = b1s[j];
#pragma unroll
        for (int mt = 0; mt < 4; ++mt) {
            int rbase = wm * 64 + mt * 16 + q * 4;
#pragma unroll
            for (int r = 0; r < 4; ++r) {
                float h = fmaxf(acc[mt][nt][r] + bj, 0.0f);
                hs[(rbase + r) * 136 + j] = f2bf(h);
            }
        }
    }
    __syncthreads();

    // second GEMM (128->8) + log_softmax; 4 threads per row (32 dims each)
    int row = tid >> 2;
    int part = tid & 3;
    const unsigned short* hp = &hs[row * 136 + part * 32];
    float p[8] = {0.f, 0.f, 0.f, 0.f, 0.f, 0.f, 0.f, 0.f};
#pragma unroll
    for (int ch = 0; ch < 4; ++ch) {
        uint4 c4 = *(const uint4*)(hp + ch * 8);
        unsigned int uu[4] = {c4.x, c4.y, c4.z, c4.w};
#pragma unroll
        for (int p2 = 0; p2 < 4; ++p2) {
            float h0 = bfu2f(uu[p2] & 0xFFFFu);
            float h1 = bfu2f(uu[p2] >> 16);
            int j = part * 32 + ch * 8 + p2 * 2;
            const float* w0 = &W2s[j * 8];
            const float* w1 = &W2s[(j + 1) * 8];
#pragma unroll
            for (int c = 0; c < 8; ++c) p[c] = fmaf(h0, w0[c], p[c]);
#pragma unroll
            for (int c = 0; c < 8; ++c) p[c] = fmaf(h1, w1[c], p[c]);
        }
    }
#pragma unroll
    for (int off2 = 1; off2 < 4; off2 <<= 1)
#pragma unroll
        for (int c = 0; c < 8; ++c) p[c] += __shfl_xor(p[c], off2, 4);
    int grow = n0 + row;
    if (part == 0 && grow < NN) {
        float v[8];
        float mx = -1e30f;
#pragma unroll
        for (int c = 0; c < 8; ++c) {
            v[c] = p[c] + b2s[c];
            mx = fmaxf(mx, v[c]);
        }
        float s = 0.0f;
#pragma unroll
        for (int c = 0; c < 8; ++c) s += expf(v[c] - mx);
        float ln = mx + logf(s);
        float4* p0 = (float4*)&logb0[(size_t)grow * 8];
        p0[0] = make_float4(v[0] - ln, v[1] - ln, v[2] - ln, v[3] - ln);
        p0[1] = make_float4(v[4] - ln, v[5] - ln, v[6] - ln, v[7] - ln);
    }
}

// ---------------- CSR setup kernels ----------------

__global__ __launch_bounds__(256) void deg_kernel(const int* __restrict__ dst,
                                                  int* __restrict__ cnt) {
    int e = blockIdx.x * 256 + threadIdx.x;
    if (e < EE) atomicAdd(&cnt[dst[e]], 1);
}

__global__ __launch_bounds__(256) void scan_partial_kernel(
    const int* __restrict__ cnt, int* __restrict__ partial) {
    __shared__ int sd[256];
    int t = threadIdx.x;
    int i = blockIdx.x * 256 + t;
    sd[t] = (i < NN) ? cnt[i] : 0;
    __syncthreads();
#pragma unroll
    for (int s = 128; s > 0; s >>= 1) {
        if (t < s) sd[t] += sd[t + s];
        __syncthreads();
    }
    if (t == 0) partial[blockIdx.x] = sd[0];
}

__global__ __launch_bounds__(256) void scan_tops_kernel(
    const int* __restrict__ partial, int* __restrict__ tops) {
    __shared__ int sd[256];
    int t = threadIdx.x;
    sd[t] = (t < NBLKS) ? partial[t] : 0;
    __syncthreads();
#pragma unroll
    for (int s = 1; s < 256; s <<= 1) {
        int a = sd[t];
        int b = (t >= s) ? sd[t - s] : 0;
        __syncthreads();
        sd[t] = a + b;
        __syncthreads();
    }
    if (t < NBLKS) tops[t] = (t > 0) ? sd[t - 1] : 0;
}

__global__ __launch_bounds__(256) void scan_write_kernel(
    const int* __restrict__ cnt, const int* __restrict__ tops,
    int* __restrict__ off) {
    __shared__ int sd[256];
    int t = threadIdx.x;
    int i = blockIdx.x * 256 + t;
    int v = (i < NN) ? cnt[i] : 0;
    sd[t] = v;
    __syncthreads();
#pragma unroll
    for (int s = 1; s < 256; s <<= 1) {
        int a = sd[t];
        int b = (t >= s) ? sd[t - s] : 0;
        __syncthreads();
        sd[t] = a + b;
        __syncthreads();
    }
    if (i < NN) off[i] = tops[blockIdx.x] + sd[t] - v;
    if (i == NN - 1) off[NN] = EE;
}

__global__ __launch_bounds__(256) void pos_kernel(
    const int* __restrict__ src, const int* __restrict__ dst,
    const float* __restrict__ ew, const int* __restrict__ off,
    int* __restrict__ cnt, int* __restrict__ pos,
    int2* __restrict__ perm_sw) {
    int e = blockIdx.x * 256 + threadIdx.x;
    if (e >= EE) return;
    int d = dst[e];
    int p = off[d] + atomicAdd(&cnt[d], 1);
    pos[e] = p;
    int2 sw;
    sw.x = src[e];
    sw.y = __float_as_int(ew[e]);
    perm_sw[p] = sw;
}

__global__ __launch_bounds__(256) void rvpos_kernel(const int* __restrict__ rv,
                                                    const int* __restrict__ pos,
                                                    int* __restrict__ perm_rvp) {
    int e = blockIdx.x * 256 + threadIdx.x;
    if (e >= EE) return;
    perm_rvp[pos[e]] = pos[rv[e]];
}

// xin[p] = logb0[perm_src[p]]; also unpack perm_w
__global__ __launch_bounds__(256) void init_xin_kernel(
    const int2* __restrict__ perm_sw, const float* __restrict__ logb0,
    float* __restrict__ xin, float* __restrict__ perm_w) {
    int p = blockIdx.x * 256 + threadIdx.x;
    if (p >= EE) return;
    int2 sw = perm_sw[p];
    perm_w[p] = __int_as_float(sw.y);
    const float4* pb = (const float4*)&logb0[(size_t)sw.x * 8];
    float4 a = pb[0], b = pb[1];
    float4* po = (float4*)&xin[(size_t)p * 8];
    po[0] = a;
    po[1] = b;
}

// ---------------- hot loop (streaming edge, scatter in node) ---------------
// Messages are deliberately UNNORMALIZED (per-edge normalizer is channel-
// uniform -> cancels in node normalize and in the xin = v - msg chain).

__global__ __launch_bounds__(256) void edge_msg_kernel(
    const float* __restrict__ perm_w, const float* __restrict__ logH,
    const float* __restrict__ xin, float* __restrict__ msg_out) {
    __shared__ float lH[64];
    if (threadIdx.x < 64) lH[threadIdx.x] = logH[threadIdx.x];
    __syncthreads();
    int p = blockIdx.x * 256 + threadIdx.x;
    if (p >= EE) return;

    float w = perm_w[p];
    const float4* pb = (const float4*)&xin[(size_t)p * 8];
    float4 v0 = pb[0], v1 = pb[1];
    float xj[8] = {v0.x, v0.y, v0.z, v0.w, v1.x, v1.y, v1.z, v1.w};

    float M = xj[0];
#pragma unroll
    for (int c = 1; c < 8; ++c) M = fmaxf(M, xj[c]);
#pragma unroll
    for (int c = 0; c < 8; ++c) xj[c] -= M;

    float mg[8];
#pragma unroll
    for (int c2 = 0; c2 < 8; ++c2) {
        float ssum = 0.0f;
#pragma unroll
        for (int c1 = 0; c1 < 8; ++c1)
            ssum += __expf(fmaf(w, lH[c1 * 8 + c2], xj[c1]));
        mg[c2] = M + __logf(ssum);  // raw (unnormalized) message
    }

    float4* po = (float4*)&msg_out[(size_t)p * 8];
    po[0] = make_float4(mg[0], mg[1], mg[2], mg[3]);
    po[1] = make_float4(mg[4], mg[5], mg[6], mg[7]);
}

__global__ __launch_bounds__(256) void node_agg_kernel(
    const float* __restrict__ logb0, const int* __restrict__ off,
    const float* __restrict__ msg, const int* __restrict__ perm_rvp,
    float* __restrict__ xin, float* __restrict__ out, int write_out) {
    int t = blockIdx.x * 256 + threadIdx.x;
    int n = t >> 3;
    int c = t & 7;
    if (n >= NN) return;
    int j0 = off[n], j1 = off[n + 1];
    float a = logb0[(size_t)n * 8 + c];
    for (int j = j0; j < j1; ++j) a += msg[(size_t)j * 8 + c];
    float mx = a;
#pragma unroll
    for (int s = 1; s < 8; s <<= 1) mx = fmaxf(mx, __shfl_xor(mx, s, 8));
    float ex = __expf(a - mx);
    float sum = ex;
#pragma unroll
    for (int s = 1; s < 8; s <<= 1) sum += __shfl_xor(sum, s, 8);
    float v = a - (mx + __logf(sum));
    if (write_out) {
        out[(size_t)n * 8 + c] = v;
    } else {
        for (int j = j0; j < j1; ++j) {
            int r = perm_rvp[j];
            xin[(size_t)r * 8 + c] = v - msg[(size_t)j * 8 + c];
        }
    }
}

extern "C" void kernel_launch(void* const* d_in, const int* in_sizes, int n_in,
                              void* d_out, int out_size, void* d_ws, size_t ws_size,
                              hipStream_t stream) {
    const float* x = (const float*)d_in[0];
    const int* ei = (const int*)d_in[1];
    const float* ew = (const float*)d_in[2];
    const int* rv = (const int*)d_in[3];
    const float* W1 = (const float*)d_in[4];
    const float* b1 = (const float*)d_in[5];
    const float* W2 = (const float*)d_in[6];
    const float* b2 = (const float*)d_in[7];
    const float* param = (const float*)d_in[8];
    float* out = (float*)d_out;

    const int* src = ei;
    const int* dst = ei + EE;

    float* wsf = (float*)d_ws;
    float* logH = wsf;                          // 64
    float* logb0 = logH + 64;                   // 400000
    float* msg = logb0 + (size_t)NN * 8;        // 6.4M
    float* xin = msg + (size_t)EE * 8;          // 6.4M
    float* perm_w = xin + (size_t)EE * 8;       // 800000
    int* off = (int*)(perm_w + EE);             // 50001
    int2* perm_sw = (int2*)(off + (NN + 1));    // 800000 int2
    int* perm_rvp = (int*)(perm_sw + EE);       // 800000
    unsigned short* W1t = (unsigned short*)(perm_rvp + EE);  // 65536 bf16
    // setup-only scratch aliases xin (first written by init_xin after setup)
    int* pos = (int*)xin;                       // 800000
    int* cnt = pos + EE;                        // 50000
    int* partial = cnt + NN;                    // 196
    int* tops = partial + NBLKS;                // 196

    logH_kernel<<<1, 64, 0, stream>>>(param, logH);
    w1t_kernel<<<256, 256, 0, stream>>>(W1, W1t);
    mlp_mfma_kernel<<<(NN + 127) / 128, 512, 0, stream>>>(x, W1t, b1, W2, b2,
                                                          logb0);

    const int EB = (EE + 255) / 256;

    hipMemsetAsync(cnt, 0, (size_t)NN * sizeof(int), stream);
    deg_kernel<<<EB, 256, 0, stream>>>(dst, cnt);
    scan_partial_kernel<<<NBLKS, 256, 0, stream>>>(cnt, partial);
    scan_tops_kernel<<<1, 256, 0, stream>>>(partial, tops);
    scan_write_kernel<<<NBLKS, 256, 0, stream>>>(cnt, tops, off);
    hipMemsetAsync(cnt, 0, (size_t)NN * sizeof(int), stream);
    pos_kernel<<<EB, 256, 0, stream>>>(src, dst, ew, off, cnt, pos, perm_sw);
    rvpos_kernel<<<EB, 256, 0, stream>>>(rv, pos, perm_rvp);
    init_xin_kernel<<<EB, 256, 0, stream>>>(perm_sw, logb0, xin, perm_w);

    for (int it = 0; it < KIT; ++it) {
        edge_msg_kernel<<<EB, 256, 0, stream>>>(perm_w, logH, xin, msg);
        node_agg_kernel<<<(NN * 8 + 255) / 256, 256, 0, stream>>>(
            logb0, off, msg, perm_rvp, xin, out, it == KIT - 1 ? 1 : 0);
    }
}

// Round 10
// 503.883 us; speedup vs baseline: 1.0534x; 1.0430x over previous
//
#include <hip/hip_runtime.h>
#include <hip/hip_bf16.h>
#include <math.h>

#define NN 50000
#define EE 800000
#define DINK 512
#define DHK 128
#define CK 8
#define KIT 5
#define NBLKS 196  // ceil(NN/256)

typedef __attribute__((ext_vector_type(8))) short short8;
typedef __attribute__((ext_vector_type(4))) float f32x4;

__device__ __forceinline__ unsigned short f2bf(float f) {
    union { float f; unsigned int u; } v;
    v.f = f;
    unsigned int u = v.u;
    unsigned int r = (u + 0x7FFFu + ((u >> 16) & 1u)) >> 16;  // RNE
    return (unsigned short)r;
}
__device__ __forceinline__ float bfu2f(unsigned int lo16) {
    union { unsigned int u; float f; } v;
    v.u = lo16 << 16;
    return v.f;
}

// logH[i][j] = log_sigmoid(param[i][j] + param[j][i]), 8x8
__global__ __launch_bounds__(64) void logH_kernel(const float* __restrict__ param,
                                                  float* __restrict__ logH) {
    int t = threadIdx.x;
    int i = t >> 3, j = t & 7;
    float z = param[i * 8 + j] + param[j * 8 + i];
    logH[t] = fminf(z, 0.0f) - log1pf(expf(-fabsf(z)));
}

// W1 [512][128] fp32 -> W1t [128][512] bf16
__global__ __launch_bounds__(256) void w1t_kernel(const float* __restrict__ W1,
                                                  unsigned short* __restrict__ W1t) {
    int idx = blockIdx.x * 256 + threadIdx.x;  // 65536
    int n = idx >> 9;
    int k = idx & 511;
    W1t[idx] = f2bf(W1[(size_t)k * DHK + n]);
}

// MFMA MLP (R7-proven version: 256 thr, VGPR ~100, ~69us — do not constrain
// registers; the 1-deep prefetch needs them. block=512 variant spilled @36 VGPR.)
__global__ __launch_bounds__(256) void mlp_mfma_kernel(
    const float* __restrict__ x, const unsigned short* __restrict__ W1t,
    const float* __restrict__ b1, const float* __restrict__ W2,
    const float* __restrict__ b2, float* __restrict__ logb0) {
    __shared__ unsigned short hs[128 * 136];
    __shared__ float W2s[128 * 8];
    __shared__ float b1s[128];
    __shared__ float b2s[8];

    const int tid = threadIdx.x;
    const int wave = tid >> 6;
    const int lane = tid & 63;
    const int q = lane >> 4;
    const int lm = lane & 15;
    const int wm = wave >> 1, wn = wave & 1;
    const int n0 = blockIdx.x * 128;

    if (tid < 128) b1s[tid] = b1[tid];
    if (tid < 8) b2s[tid] = b2[tid];
    {
        int i = tid * 4;
        *(float4*)&W2s[i] = *(const float4*)&W2[i];
    }
    __syncthreads();

    const float* xptr[4];
#pragma unroll
    for (int mt = 0; mt < 4; ++mt) {
        int r = n0 + wm * 64 + mt * 16 + lm;
        if (r > NN - 1) r = NN - 1;
        xptr[mt] = x + (size_t)r * DINK + q * 8;
    }
    const unsigned short* bptr[4];
#pragma unroll
    for (int nt = 0; nt < 4; ++nt) {
        int c = wn * 64 + nt * 16 + lm;
        bptr[nt] = W1t + (size_t)c * DINK + q * 8;
    }

    f32x4 acc[4][4];
#pragma unroll
    for (int mt = 0; mt < 4; ++mt)
#pragma unroll
        for (int nt = 0; nt < 4; ++nt) acc[mt][nt] = (f32x4){0.f, 0.f, 0.f, 0.f};

    float4 ar[4][2];
    short8 bc[4];
#pragma unroll
    for (int mt = 0; mt < 4; ++mt) {
        ar[mt][0] = *(const float4*)(xptr[mt]);
        ar[mt][1] = *(const float4*)(xptr[mt] + 4);
    }
#pragma unroll
    for (int nt = 0; nt < 4; ++nt) bc[nt] = *(const short8*)(bptr[nt]);

#pragma unroll
    for (int k0 = 32; k0 <= DINK; k0 += 32) {
        float4 ar2[4][2];
        short8 b2f[4];
        if (k0 < DINK) {
#pragma unroll
            for (int mt = 0; mt < 4; ++mt) {
                ar2[mt][0] = *(const float4*)(xptr[mt] + k0);
                ar2[mt][1] = *(const float4*)(xptr[mt] + k0 + 4);
            }
#pragma unroll
            for (int nt = 0; nt < 4; ++nt)
                b2f[nt] = *(const short8*)(bptr[nt] + k0);
        }
        short8 af[4];
#pragma unroll
        for (int mt = 0; mt < 4; ++mt) {
            union { short8 s; __hip_bfloat162 h[4]; } cv;
            cv.h[0] = __float22bfloat162_rn(make_float2(ar[mt][0].x, ar[mt][0].y));
            cv.h[1] = __float22bfloat162_rn(make_float2(ar[mt][0].z, ar[mt][0].w));
            cv.h[2] = __float22bfloat162_rn(make_float2(ar[mt][1].x, ar[mt][1].y));
            cv.h[3] = __float22bfloat162_rn(make_float2(ar[mt][1].z, ar[mt][1].w));
            af[mt] = cv.s;
        }
#pragma unroll
        for (int mt = 0; mt < 4; ++mt)
#pragma unroll
            for (int nt = 0; nt < 4; ++nt)
                acc[mt][nt] = __builtin_amdgcn_mfma_f32_16x16x32_bf16(
                    af[mt], bc[nt], acc[mt][nt], 0, 0, 0);
        if (k0 < DINK) {
#pragma unroll
            for (int mt = 0; mt < 4; ++mt) {
                ar[mt][0] = ar2[mt][0];
                ar[mt][1] = ar2[mt][1];
            }
#pragma unroll
            for (int nt = 0; nt < 4; ++nt) bc[nt] = b2f[nt];
        }
    }

#pragma unroll
    for (int nt = 0; nt < 4; ++nt) {
        int j = wn * 64 + nt * 16 + lm;
        float bj = b1s[j];
#pragma unroll
        for (int mt = 0; mt < 4; ++mt) {
            int rbase = wm * 64 + mt * 16 + q * 4;
#pragma unroll
            for (int r = 0; r < 4; ++r) {
                float h = fmaxf(acc[mt][nt][r] + bj, 0.0f);
                hs[(rbase + r) * 136 + j] = f2bf(h);
            }
        }
    }
    __syncthreads();

    int row = tid >> 1;
    int half = tid & 1;
    const unsigned short* hp = &hs[row * 136 + half * 64];
    float p[8] = {0.f, 0.f, 0.f, 0.f, 0.f, 0.f, 0.f, 0.f};
#pragma unroll
    for (int ch = 0; ch < 8; ++ch) {
        uint4 c4 = *(const uint4*)(hp + ch * 8);
        unsigned int uu[4] = {c4.x, c4.y, c4.z, c4.w};
#pragma unroll
        for (int p2 = 0; p2 < 4; ++p2) {
            float h0 = bfu2f(uu[p2] & 0xFFFFu);
            float h1 = bfu2f(uu[p2] >> 16);
            int j = half * 64 + ch * 8 + p2 * 2;
            const float* w0 = &W2s[j * 8];
            const float* w1 = &W2s[(j + 1) * 8];
#pragma unroll
            for (int c = 0; c < 8; ++c) p[c] = fmaf(h0, w0[c], p[c]);
#pragma unroll
            for (int c = 0; c < 8; ++c) p[c] = fmaf(h1, w1[c], p[c]);
        }
    }
#pragma unroll
    for (int c = 0; c < 8; ++c) p[c] += __shfl_xor(p[c], 1, 64);
    int grow = n0 + row;
    if (half == 0 && grow < NN) {
        float v[8];
        float mx = -1e30f;
#pragma unroll
        for (int c = 0; c < 8; ++c) {
            v[c] = p[c] + b2s[c];
            mx = fmaxf(mx, v[c]);
        }
        float s = 0.0f;
#pragma unroll
        for (int c = 0; c < 8; ++c) s += expf(v[c] - mx);
        float ln = mx + logf(s);
        float4* p0 = (float4*)&logb0[(size_t)grow * 8];
        p0[0] = make_float4(v[0] - ln, v[1] - ln, v[2] - ln, v[3] - ln);
        p0[1] = make_float4(v[4] - ln, v[5] - ln, v[6] - ln, v[7] - ln);
    }
}

// ---------------- CSR setup kernels ----------------

__global__ __launch_bounds__(256) void deg_kernel(const int* __restrict__ dst,
                                                  int* __restrict__ cnt) {
    int e = blockIdx.x * 256 + threadIdx.x;
    if (e < EE) atomicAdd(&cnt[dst[e]], 1);
}

__global__ __launch_bounds__(256) void scan_partial_kernel(
    const int* __restrict__ cnt, int* __restrict__ partial) {
    __shared__ int sd[256];
    int t = threadIdx.x;
    int i = blockIdx.x * 256 + t;
    sd[t] = (i < NN) ? cnt[i] : 0;
    __syncthreads();
#pragma unroll
    for (int s = 128; s > 0; s >>= 1) {
        if (t < s) sd[t] += sd[t + s];
        __syncthreads();
    }
    if (t == 0) partial[blockIdx.x] = sd[0];
}

__global__ __launch_bounds__(256) void scan_tops_kernel(
    const int* __restrict__ partial, int* __restrict__ tops) {
    __shared__ int sd[256];
    int t = threadIdx.x;
    sd[t] = (t < NBLKS) ? partial[t] : 0;
    __syncthreads();
#pragma unroll
    for (int s = 1; s < 256; s <<= 1) {
        int a = sd[t];
        int b = (t >= s) ? sd[t - s] : 0;
        __syncthreads();
        sd[t] = a + b;
        __syncthreads();
    }
    if (t < NBLKS) tops[t] = (t > 0) ? sd[t - 1] : 0;
}

__global__ __launch_bounds__(256) void scan_write_kernel(
    const int* __restrict__ cnt, const int* __restrict__ tops,
    int* __restrict__ off) {
    __shared__ int sd[256];
    int t = threadIdx.x;
    int i = blockIdx.x * 256 + t;
    int v = (i < NN) ? cnt[i] : 0;
    sd[t] = v;
    __syncthreads();
#pragma unroll
    for (int s = 1; s < 256; s <<= 1) {
        int a = sd[t];
        int b = (t >= s) ? sd[t - s] : 0;
        __syncthreads();
        sd[t] = a + b;
        __syncthreads();
    }
    if (i < NN) off[i] = tops[blockIdx.x] + sd[t] - v;
    if (i == NN - 1) off[NN] = EE;
}

__global__ __launch_bounds__(256) void pos_kernel(
    const int* __restrict__ src, const int* __restrict__ dst,
    const float* __restrict__ ew, const int* __restrict__ off,
    int* __restrict__ cnt, int* __restrict__ pos,
    int2* __restrict__ perm_sw, int* __restrict__ perm_dst) {
    int e = blockIdx.x * 256 + threadIdx.x;
    if (e >= EE) return;
    int d = dst[e];
    int p = off[d] + atomicAdd(&cnt[d], 1);
    pos[e] = p;
    int2 sw;
    sw.x = src[e];
    sw.y = __float_as_int(ew[e]);
    perm_sw[p] = sw;
    perm_dst[p] = d;
}

__global__ __launch_bounds__(256) void rvpos_kernel(const int* __restrict__ rv,
                                                    const int* __restrict__ pos,
                                                    int* __restrict__ perm_rvp) {
    int e = blockIdx.x * 256 + threadIdx.x;
    if (e >= EE) return;
    perm_rvp[pos[e]] = pos[rv[e]];
}

// xin[p] = logb0[perm_src[p]]; also unpack perm_w
__global__ __launch_bounds__(256) void init_xin_kernel(
    const int2* __restrict__ perm_sw, const float* __restrict__ logb0,
    float* __restrict__ xin, float* __restrict__ perm_w) {
    int p = blockIdx.x * 256 + threadIdx.x;
    if (p >= EE) return;
    int2 sw = perm_sw[p];
    perm_w[p] = __int_as_float(sw.y);
    const float4* pb = (const float4*)&logb0[(size_t)sw.x * 8];
    float4 a = pb[0], b = pb[1];
    float4* po = (float4*)&xin[(size_t)p * 8];
    po[0] = a;
    po[1] = b;
}

// ---------------- hot loop (3 kernels, all non-divergent inner work) --------
// Messages deliberately UNNORMALIZED (per-edge normalizer is channel-uniform
// -> cancels in node normalize and in the xin = belief - msg chain).

__global__ __launch_bounds__(256) void edge_msg_kernel(
    const float* __restrict__ perm_w, const float* __restrict__ logH,
    const float* __restrict__ xin, float* __restrict__ msg_out) {
    __shared__ float lH[64];
    if (threadIdx.x < 64) lH[threadIdx.x] = logH[threadIdx.x];
    __syncthreads();
    int p = blockIdx.x * 256 + threadIdx.x;
    if (p >= EE) return;

    float w = perm_w[p];
    const float4* pb = (const float4*)&xin[(size_t)p * 8];
    float4 v0 = pb[0], v1 = pb[1];
    float xj[8] = {v0.x, v0.y, v0.z, v0.w, v1.x, v1.y, v1.z, v1.w};

    float M = xj[0];
#pragma unroll
    for (int c = 1; c < 8; ++c) M = fmaxf(M, xj[c]);
#pragma unroll
    for (int c = 0; c < 8; ++c) xj[c] -= M;

    float mg[8];
#pragma unroll
    for (int c2 = 0; c2 < 8; ++c2) {
        float ssum = 0.0f;
#pragma unroll
        for (int c1 = 0; c1 < 8; ++c1)
            ssum += __expf(fmaf(w, lH[c1 * 8 + c2], xj[c1]));
        mg[c2] = M + __logf(ssum);  // raw (unnormalized) message
    }

    float4* po = (float4*)&msg_out[(size_t)p * 8];
    po[0] = make_float4(mg[0], mg[1], mg[2], mg[3]);
    po[1] = make_float4(mg[4], mg[5], mg[6], mg[7]);
}

// 8 threads/node: aggregate contiguous msg range, normalize, write belief
// (or final output). No scatter here.
__global__ __launch_bounds__(256) void node_belief_kernel(
    const float* __restrict__ logb0, const int* __restrict__ off,
    const float* __restrict__ msg, float* __restrict__ belief,
    float* __restrict__ out, int write_out) {
    int t = blockIdx.x * 256 + threadIdx.x;
    int n = t >> 3;
    int c = t & 7;
    if (n >= NN) return;
    int j0 = off[n], j1 = off[n + 1];
    float a = logb0[(size_t)n * 8 + c];
    for (int j = j0; j < j1; ++j) a += msg[(size_t)j * 8 + c];
    float mx = a;
#pragma unroll
    for (int s = 1; s < 8; s <<= 1) mx = fmaxf(mx, __shfl_xor(mx, s, 8));
    float ex = __expf(a - mx);
    float sum = ex;
#pragma unroll
    for (int s = 1; s < 8; s <<= 1) sum += __shfl_xor(sum, s, 8);
    float v = a - (mx + __logf(sum));
    if (write_out) out[(size_t)n * 8 + c] = v;
    else belief[(size_t)n * 8 + c] = v;
}

// Edge-parallel next-iter input build: dst(rv(p)) == src(p), so
// xin[rvp[p]] = belief[perm_dst[p]] - msg[p]. All reads contiguous or L2-hot;
// the random op is a fire-and-forget 32B store. No divergence.
__global__ __launch_bounds__(256) void edge_scatter_kernel(
    const int* __restrict__ perm_dst, const int* __restrict__ perm_rvp,
    const float* __restrict__ belief, const float* __restrict__ msg,
    float* __restrict__ xin) {
    int p = blockIdx.x * 256 + threadIdx.x;
    if (p >= EE) return;
    int d = perm_dst[p];
    int r = perm_rvp[p];
    const float4* pb = (const float4*)&belief[(size_t)d * 8];
    float4 b0 = pb[0], b1 = pb[1];
    const float4* pm = (const float4*)&msg[(size_t)p * 8];
    float4 m0 = pm[0], m1 = pm[1];
    float4* po = (float4*)&xin[(size_t)r * 8];
    po[0] = make_float4(b0.x - m0.x, b0.y - m0.y, b0.z - m0.z, b0.w - m0.w);
    po[1] = make_float4(b1.x - m1.x, b1.y - m1.y, b1.z - m1.z, b1.w - m1.w);
}

extern "C" void kernel_launch(void* const* d_in, const int* in_sizes, int n_in,
                              void* d_out, int out_size, void* d_ws, size_t ws_size,
                              hipStream_t stream) {
    const float* x = (const float*)d_in[0];
    const int* ei = (const int*)d_in[1];
    const float* ew = (const float*)d_in[2];
    const int* rv = (const int*)d_in[3];
    const float* W1 = (const float*)d_in[4];
    const float* b1 = (const float*)d_in[5];
    const float* W2 = (const float*)d_in[6];
    const float* b2 = (const float*)d_in[7];
    const float* param = (const float*)d_in[8];
    float* out = (float*)d_out;

    const int* src = ei;
    const int* dst = ei + EE;

    float* wsf = (float*)d_ws;
    float* logH = wsf;                          // 64
    float* logb0 = logH + 64;                   // 400000
    float* belief = logb0 + (size_t)NN * 8;     // 400000
    float* msg = belief + (size_t)NN * 8;       // 6.4M
    float* xin = msg + (size_t)EE * 8;          // 6.4M
    float* perm_w = xin + (size_t)EE * 8;       // 800000
    int* off = (int*)(perm_w + EE);             // 50001
    int2* perm_sw = (int2*)(off + (NN + 1));    // 800000 int2
    int* perm_rvp = (int*)(perm_sw + EE);       // 800000
    int* perm_dst = perm_rvp + EE;              // 800000
    unsigned short* W1t = (unsigned short*)(perm_dst + EE);  // 65536 bf16
    // setup-only scratch aliases xin (first written by init_xin after setup)
    int* pos = (int*)xin;                       // 800000
    int* cnt = pos + EE;                        // 50000
    int* partial = cnt + NN;                    // 196
    int* tops = partial + NBLKS;                // 196

    logH_kernel<<<1, 64, 0, stream>>>(param, logH);
    w1t_kernel<<<256, 256, 0, stream>>>(W1, W1t);
    mlp_mfma_kernel<<<(NN + 127) / 128, 256, 0, stream>>>(x, W1t, b1, W2, b2,
                                                          logb0);

    const int EB = (EE + 255) / 256;

    hipMemsetAsync(cnt, 0, (size_t)NN * sizeof(int), stream);
    deg_kernel<<<EB, 256, 0, stream>>>(dst, cnt);
    scan_partial_kernel<<<NBLKS, 256, 0, stream>>>(cnt, partial);
    scan_tops_kernel<<<1, 256, 0, stream>>>(partial, tops);
    scan_write_kernel<<<NBLKS, 256, 0, stream>>>(cnt, tops, off);
    hipMemsetAsync(cnt, 0, (size_t)NN * sizeof(int), stream);
    pos_kernel<<<EB, 256, 0, stream>>>(src, dst, ew, off, cnt, pos, perm_sw,
                                       perm_dst);
    rvpos_kernel<<<EB, 256, 0, stream>>>(rv, pos, perm_rvp);
    init_xin_kernel<<<EB, 256, 0, stream>>>(perm_sw, logb0, xin, perm_w);

    const int NB8 = (NN * 8 + 255) / 256;
    for (int it = 0; it < KIT; ++it) {
        int last = (it == KIT - 1) ? 1 : 0;
        edge_msg_kernel<<<EB, 256, 0, stream>>>(perm_w, logH, xin, msg);
        node_belief_kernel<<<NB8, 256, 0, stream>>>(logb0, off, msg, belief,
                                                    out, last);
        if (!last)
            edge_scatter_kernel<<<EB, 256, 0, stream>>>(perm_dst, perm_rvp,
                                                        belief, msg, xin);
    }
}

// Round 12
// 486.113 us; speedup vs baseline: 1.0919x; 1.0366x over previous
//
#include <hip/hip_runtime.h>
#include <hip/hip_bf16.h>
#include <math.h>

#define NN 50000
#define EE 800000
#define DINK 512
#define DHK 128
#define CK 8
#define KIT 5
#define NBLKS 196  // ceil(NN/256)
#define NPB 32     // nodes per node_fused block

typedef __attribute__((ext_vector_type(8))) short short8;
typedef __attribute__((ext_vector_type(4))) float f32x4;

__device__ __forceinline__ unsigned short f2bf(float f) {
    union { float f; unsigned int u; } v;
    v.f = f;
    unsigned int u = v.u;
    unsigned int r = (u + 0x7FFFu + ((u >> 16) & 1u)) >> 16;  // RNE
    return (unsigned short)r;
}
__device__ __forceinline__ float bfu2f(unsigned int lo16) {
    union { unsigned int u; float f; } v;
    v.u = lo16 << 16;
    return v.f;
}

// merged prep: blocks 0..255 transpose W1 -> bf16 W1t; block 256 computes logH
__global__ __launch_bounds__(256) void prep_kernel(
    const float* __restrict__ W1, const float* __restrict__ param,
    unsigned short* __restrict__ W1t, float* __restrict__ logH) {
    if (blockIdx.x < 256) {
        int idx = blockIdx.x * 256 + threadIdx.x;  // 65536
        int n = idx >> 9;
        int k = idx & 511;
        W1t[idx] = f2bf(W1[(size_t)k * DHK + n]);
    } else if (threadIdx.x < 64) {
        int t = threadIdx.x;
        int i = t >> 3, j = t & 7;
        float z = param[i * 8 + j] + param[j * 8 + i];
        logH[t] = fminf(z, 0.0f) - log1pf(expf(-fabsf(z)));
    }
}

// MFMA MLP (R7-proven: 256 thr, VGPR ~100, ~69us; do not constrain registers —
// the 512-thr variant squeezed to 36 VGPR and regressed to 103us)
__global__ __launch_bounds__(256) void mlp_mfma_kernel(
    const float* __restrict__ x, const unsigned short* __restrict__ W1t,
    const float* __restrict__ b1, const float* __restrict__ W2,
    const float* __restrict__ b2, float* __restrict__ logb0) {
    __shared__ unsigned short hs[128 * 136];
    __shared__ float W2s[128 * 8];
    __shared__ float b1s[128];
    __shared__ float b2s[8];

    const int tid = threadIdx.x;
    const int wave = tid >> 6;
    const int lane = tid & 63;
    const int q = lane >> 4;
    const int lm = lane & 15;
    const int wm = wave >> 1, wn = wave & 1;
    const int n0 = blockIdx.x * 128;

    if (tid < 128) b1s[tid] = b1[tid];
    if (tid < 8) b2s[tid] = b2[tid];
    {
        int i = tid * 4;
        *(float4*)&W2s[i] = *(const float4*)&W2[i];
    }
    __syncthreads();

    const float* xptr[4];
#pragma unroll
    for (int mt = 0; mt < 4; ++mt) {
        int r = n0 + wm * 64 + mt * 16 + lm;
        if (r > NN - 1) r = NN - 1;
        xptr[mt] = x + (size_t)r * DINK + q * 8;
    }
    const unsigned short* bptr[4];
#pragma unroll
    for (int nt = 0; nt < 4; ++nt) {
        int c = wn * 64 + nt * 16 + lm;
        bptr[nt] = W1t + (size_t)c * DINK + q * 8;
    }

    f32x4 acc[4][4];
#pragma unroll
    for (int mt = 0; mt < 4; ++mt)
#pragma unroll
        for (int nt = 0; nt < 4; ++nt) acc[mt][nt] = (f32x4){0.f, 0.f, 0.f, 0.f};

    float4 ar[4][2];
    short8 bc[4];
#pragma unroll
    for (int mt = 0; mt < 4; ++mt) {
        ar[mt][0] = *(const float4*)(xptr[mt]);
        ar[mt][1] = *(const float4*)(xptr[mt] + 4);
    }
#pragma unroll
    for (int nt = 0; nt < 4; ++nt) bc[nt] = *(const short8*)(bptr[nt]);

#pragma unroll
    for (int k0 = 32; k0 <= DINK; k0 += 32) {
        float4 ar2[4][2];
        short8 b2f[4];
        if (k0 < DINK) {
#pragma unroll
            for (int mt = 0; mt < 4; ++mt) {
                ar2[mt][0] = *(const float4*)(xptr[mt] + k0);
                ar2[mt][1] = *(const float4*)(xptr[mt] + k0 + 4);
            }
#pragma unroll
            for (int nt = 0; nt < 4; ++nt)
                b2f[nt] = *(const short8*)(bptr[nt] + k0);
        }
        short8 af[4];
#pragma unroll
        for (int mt = 0; mt < 4; ++mt) {
            union { short8 s; __hip_bfloat162 h[4]; } cv;
            cv.h[0] = __float22bfloat162_rn(make_float2(ar[mt][0].x, ar[mt][0].y));
            cv.h[1] = __float22bfloat162_rn(make_float2(ar[mt][0].z, ar[mt][0].w));
            cv.h[2] = __float22bfloat162_rn(make_float2(ar[mt][1].x, ar[mt][1].y));
            cv.h[3] = __float22bfloat162_rn(make_float2(ar[mt][1].z, ar[mt][1].w));
            af[mt] = cv.s;
        }
#pragma unroll
        for (int mt = 0; mt < 4; ++mt)
#pragma unroll
            for (int nt = 0; nt < 4; ++nt)
                acc[mt][nt] = __builtin_amdgcn_mfma_f32_16x16x32_bf16(
                    af[mt], bc[nt], acc[mt][nt], 0, 0, 0);
        if (k0 < DINK) {
#pragma unroll
            for (int mt = 0; mt < 4; ++mt) {
                ar[mt][0] = ar2[mt][0];
                ar[mt][1] = ar2[mt][1];
            }
#pragma unroll
            for (int nt = 0; nt < 4; ++nt) bc[nt] = b2f[nt];
        }
    }

#pragma unroll
    for (int nt = 0; nt < 4; ++nt) {
        int j = wn * 64 + nt * 16 + lm;
        float bj = b1s[j];
#pragma unroll
        for (int mt = 0; mt < 4; ++mt) {
            int rbase = wm * 64 + mt * 16 + q * 4;
#pragma unroll
            for (int r = 0; r < 4; ++r) {
                float h = fmaxf(acc[mt][nt][r] + bj, 0.0f);
                hs[(rbase + r) * 136 + j] = f2bf(h);
            }
        }
    }
    __syncthreads();

    int row = tid >> 1;
    int half = tid & 1;
    const unsigned short* hp = &hs[row * 136 + half * 64];
    float p[8] = {0.f, 0.f, 0.f, 0.f, 0.f, 0.f, 0.f, 0.f};
#pragma unroll
    for (int ch = 0; ch < 8; ++ch) {
        uint4 c4 = *(const uint4*)(hp + ch * 8);
        unsigned int uu[4] = {c4.x, c4.y, c4.z, c4.w};
#pragma unroll
        for (int p2 = 0; p2 < 4; ++p2) {
            float h0 = bfu2f(uu[p2] & 0xFFFFu);
            float h1 = bfu2f(uu[p2] >> 16);
            int j = half * 64 + ch * 8 + p2 * 2;
            const float* w0 = &W2s[j * 8];
            const float* w1 = &W2s[(j + 1) * 8];
#pragma unroll
            for (int c = 0; c < 8; ++c) p[c] = fmaf(h0, w0[c], p[c]);
#pragma unroll
            for (int c = 0; c < 8; ++c) p[c] = fmaf(h1, w1[c], p[c]);
        }
    }
#pragma unroll
    for (int c = 0; c < 8; ++c) p[c] += __shfl_xor(p[c], 1, 64);
    int grow = n0 + row;
    if (half == 0 && grow < NN) {
        float v[8];
        float mx = -1e30f;
#pragma unroll
        for (int c = 0; c < 8; ++c) {
            v[c] = p[c] + b2s[c];
            mx = fmaxf(mx, v[c]);
        }
        float s = 0.0f;
#pragma unroll
        for (int c = 0; c < 8; ++c) s += expf(v[c] - mx);
        float ln = mx + logf(s);
        float4* p0 = (float4*)&logb0[(size_t)grow * 8];
        p0[0] = make_float4(v[0] - ln, v[1] - ln, v[2] - ln, v[3] - ln);
        p0[1] = make_float4(v[4] - ln, v[5] - ln, v[6] - ln, v[7] - ln);
    }
}

// ---------------- CSR setup kernels ----------------

__global__ __launch_bounds__(256) void deg_kernel(const int* __restrict__ dst,
                                                  int* __restrict__ cnt) {
    int e = blockIdx.x * 256 + threadIdx.x;
    if (e < EE) atomicAdd(&cnt[dst[e]], 1);
}

__global__ __launch_bounds__(256) void scan_partial_kernel(
    const int* __restrict__ cnt, int* __restrict__ partial) {
    __shared__ int sd[256];
    int t = threadIdx.x;
    int i = blockIdx.x * 256 + t;
    sd[t] = (i < NN) ? cnt[i] : 0;
    __syncthreads();
#pragma unroll
    for (int s = 128; s > 0; s >>= 1) {
        if (t < s) sd[t] += sd[t + s];
        __syncthreads();
    }
    if (t == 0) partial[blockIdx.x] = sd[0];
}

__global__ __launch_bounds__(256) void scan_tops_kernel(
    const int* __restrict__ partial, int* __restrict__ tops) {
    __shared__ int sd[256];
    int t = threadIdx.x;
    sd[t] = (t < NBLKS) ? partial[t] : 0;
    __syncthreads();
#pragma unroll
    for (int s = 1; s < 256; s <<= 1) {
        int a = sd[t];
        int b = (t >= s) ? sd[t - s] : 0;
        __syncthreads();
        sd[t] = a + b;
        __syncthreads();
    }
    if (t < NBLKS) tops[t] = (t > 0) ? sd[t - 1] : 0;
}

__global__ __launch_bounds__(256) void scan_write_kernel(
    const int* __restrict__ cnt, const int* __restrict__ tops,
    int* __restrict__ off) {
    __shared__ int sd[256];
    int t = threadIdx.x;
    int i = blockIdx.x * 256 + t;
    int v = (i < NN) ? cnt[i] : 0;
    sd[t] = v;
    __syncthreads();
#pragma unroll
    for (int s = 1; s < 256; s <<= 1) {
        int a = sd[t];
        int b = (t >= s) ? sd[t - s] : 0;
        __syncthreads();
        sd[t] = a + b;
        __syncthreads();
    }
    if (i < NN) off[i] = tops[blockIdx.x] + sd[t] - v;
    if (i == NN - 1) off[NN] = EE;
}

__global__ __launch_bounds__(256) void pos_kernel(
    const int* __restrict__ src, const int* __restrict__ dst,
    const float* __restrict__ ew, const int* __restrict__ off,
    int* __restrict__ cnt, int* __restrict__ pos,
    int2* __restrict__ perm_sw, int* __restrict__ perm_dst) {
    int e = blockIdx.x * 256 + threadIdx.x;
    if (e >= EE) return;
    int d = dst[e];
    int p = off[d] + atomicAdd(&cnt[d], 1);
    pos[e] = p;
    int2 sw;
    sw.x = src[e];
    sw.y = __float_as_int(ew[e]);
    perm_sw[p] = sw;
    perm_dst[p] = d;
}

__global__ __launch_bounds__(256) void rvpos_kernel(const int* __restrict__ rv,
                                                    const int* __restrict__ pos,
                                                    int* __restrict__ perm_rvp) {
    int e = blockIdx.x * 256 + threadIdx.x;
    if (e >= EE) return;
    perm_rvp[pos[e]] = pos[rv[e]];
}

// ---------------- hot loop: 2 kernels/iter, no grid-wide dependency ---------
// Messages deliberately UNNORMALIZED (per-edge normalizer is channel-uniform
// -> cancels in node normalize and in the xin = belief - msg chain).

// Per-edge raw message. first=1: gather source beliefs from logb0 (L2-hot)
// instead of xin (replaces the old init_xin pass).
__global__ __launch_bounds__(256) void edge_msg_kernel(
    const int2* __restrict__ perm_sw, const float* __restrict__ logH,
    const float* __restrict__ logb0, const float* __restrict__ xin,
    float* __restrict__ msg_out, int first) {
    __shared__ float lH[64];
    if (threadIdx.x < 64) lH[threadIdx.x] = logH[threadIdx.x];
    __syncthreads();
    int p = blockIdx.x * 256 + threadIdx.x;
    if (p >= EE) return;

    int2 sw = perm_sw[p];
    float w = __int_as_float(sw.y);
    const float4* pb = first ? (const float4*)&logb0[(size_t)sw.x * 8]
                             : (const float4*)&xin[(size_t)p * 8];
    float4 v0 = pb[0], v1 = pb[1];
    float xj[8] = {v0.x, v0.y, v0.z, v0.w, v1.x, v1.y, v1.z, v1.w};

    float M = xj[0];
#pragma unroll
    for (int c = 1; c < 8; ++c) M = fmaxf(M, xj[c]);
#pragma unroll
    for (int c = 0; c < 8; ++c) xj[c] -= M;

    float mg[8];
#pragma unroll
    for (int c2 = 0; c2 < 8; ++c2) {
        float ssum = 0.0f;
#pragma unroll
        for (int c1 = 0; c1 < 8; ++c1)
            ssum += __expf(fmaf(w, lH[c1 * 8 + c2], xj[c1]));
        mg[c2] = M + __logf(ssum);  // raw (unnormalized) message
    }

    float4* po = (float4*)&msg_out[(size_t)p * 8];
    po[0] = make_float4(mg[0], mg[1], mg[2], mg[3]);
    po[1] = make_float4(mg[4], mg[5], mg[6], mg[7]);
}

// Fused node belief + scatter. Block owns nodes [n0, n0+32) whose in-edges
// are the contiguous CSR range [off[n0], off[n0+32)) — beliefs go to LDS,
// then the SAME block scatters xin[rvp[j]] = belief[dst(j)] - msg[j]
// edge-parallel (msg L1-hot from phase 1). No global belief array.
__global__ __launch_bounds__(256) void node_fused_kernel(
    const float* __restrict__ logb0, const int* __restrict__ off,
    const float* __restrict__ msg, const int* __restrict__ perm_dst,
    const int* __restrict__ perm_rvp, float* __restrict__ xin,
    float* __restrict__ out, int last) {
    __shared__ float sb[NPB * 8];
    const int n0 = blockIdx.x * NPB;
    const int t = threadIdx.x;
    const int nl = t >> 3;
    const int c = t & 7;
    const int n = n0 + nl;

    if (n < NN) {
        int j0 = off[n], j1 = off[n + 1];
        float a = logb0[(size_t)n * 8 + c];
        for (int j = j0; j < j1; ++j) a += msg[(size_t)j * 8 + c];
        float mx = a;
#pragma unroll
        for (int s = 1; s < 8; s <<= 1) mx = fmaxf(mx, __shfl_xor(mx, s, 8));
        float sum = __expf(a - mx);
#pragma unroll
        for (int s = 1; s < 8; s <<= 1) sum += __shfl_xor(sum, s, 8);
        float v = a - (mx + __logf(sum));
        if (last) out[(size_t)n * 8 + c] = v;
        sb[nl * 8 + c] = v;
    }
    if (last) return;
    __syncthreads();

    const int nend = (n0 + NPB < NN) ? (n0 + NPB) : NN;
    const int jb0 = off[n0];
    const int jb1 = off[nend];
    const int items = (jb1 - jb0) * 8;
    for (int item = t; item < items; item += 256) {
        int j = jb0 + (item >> 3);
        int c2 = item & 7;
        int dl = perm_dst[j] - n0;
        float val = sb[dl * 8 + c2] - msg[(size_t)j * 8 + c2];
        xin[(size_t)perm_rvp[j] * 8 + c2] = val;
    }
}

extern "C" void kernel_launch(void* const* d_in, const int* in_sizes, int n_in,
                              void* d_out, int out_size, void* d_ws, size_t ws_size,
                              hipStream_t stream) {
    const float* x = (const float*)d_in[0];
    const int* ei = (const int*)d_in[1];
    const float* ew = (const float*)d_in[2];
    const int* rv = (const int*)d_in[3];
    const float* W1 = (const float*)d_in[4];
    const float* b1 = (const float*)d_in[5];
    const float* W2 = (const float*)d_in[6];
    const float* b2 = (const float*)d_in[7];
    const float* param = (const float*)d_in[8];
    float* out = (float*)d_out;

    const int* src = ei;
    const int* dst = ei + EE;

    float* wsf = (float*)d_ws;
    float* logH = wsf;                          // 64
    float* logb0 = logH + 64;                   // 400000
    float* msg = logb0 + (size_t)NN * 8;        // 6.4M
    float* xin = msg + (size_t)EE * 8;          // 6.4M
    int* off = (int*)(xin + (size_t)EE * 8);    // 50001
    int2* perm_sw = (int2*)(off + (NN + 1));    // 800000 int2
    int* perm_rvp = (int*)(perm_sw + EE);       // 800000
    int* perm_dst = perm_rvp + EE;              // 800000
    unsigned short* W1t = (unsigned short*)(perm_dst + EE);  // 65536 bf16
    // setup-only scratch aliases xin (xin first written by node_fused it=0,
    // after all setup kernels complete)
    int* pos = (int*)xin;                       // 800000
    int* cnt = pos + EE;                        // 50000
    int* partial = cnt + NN;                    // 196
    int* tops = partial + NBLKS;                // 196

    prep_kernel<<<257, 256, 0, stream>>>(W1, param, W1t, logH);
    mlp_mfma_kernel<<<(NN + 127) / 128, 256, 0, stream>>>(x, W1t, b1, W2, b2,
                                                          logb0);

    const int EB = (EE + 255) / 256;

    hipMemsetAsync(cnt, 0, (size_t)NN * sizeof(int), stream);
    deg_kernel<<<EB, 256, 0, stream>>>(dst, cnt);
    scan_partial_kernel<<<NBLKS, 256, 0, stream>>>(cnt, partial);
    scan_tops_kernel<<<1, 256, 0, stream>>>(partial, tops);
    scan_write_kernel<<<NBLKS, 256, 0, stream>>>(cnt, tops, off);
    hipMemsetAsync(cnt, 0, (size_t)NN * sizeof(int), stream);
    pos_kernel<<<EB, 256, 0, stream>>>(src, dst, ew, off, cnt, pos, perm_sw,
                                       perm_dst);
    rvpos_kernel<<<EB, 256, 0, stream>>>(rv, pos, perm_rvp);

    const int NB = (NN + NPB - 1) / NPB;
    for (int it = 0; it < KIT; ++it) {
        int first = (it == 0) ? 1 : 0;
        int last = (it == KIT - 1) ? 1 : 0;
        edge_msg_kernel<<<EB, 256, 0, stream>>>(perm_sw, logH, logb0, xin, msg,
                                                first);
        node_fused_kernel<<<NB, 256, 0, stream>>>(logb0, off, msg, perm_dst,
                                                  perm_rvp, xin, out, last);
    }
}

// Round 13
// 481.244 us; speedup vs baseline: 1.1029x; 1.0101x over previous
//
#include <hip/hip_runtime.h>
#include <hip/hip_bf16.h>
#include <math.h>

#define NN 50000
#define EE 800000
#define E2K 400000
#define DINK 512
#define DHK 128
#define CK 8
#define KIT 5
#define NBLKS 196  // ceil(NN/256)
#define NPB 32     // nodes per node_fused block

typedef __attribute__((ext_vector_type(8))) short short8;
typedef __attribute__((ext_vector_type(4))) float f32x4;

__device__ __forceinline__ unsigned short f2bf(float f) {
    union { float f; unsigned int u; } v;
    v.f = f;
    unsigned int u = v.u;
    unsigned int r = (u + 0x7FFFu + ((u >> 16) & 1u)) >> 16;  // RNE
    return (unsigned short)r;
}
__device__ __forceinline__ float bfu2f(unsigned int lo16) {
    union { unsigned int u; float f; } v;
    v.u = lo16 << 16;
    return v.f;
}

// merged prep: blocks 0..255 transpose W1 -> bf16 W1t; block 256 computes logH
__global__ __launch_bounds__(256) void prep_kernel(
    const float* __restrict__ W1, const float* __restrict__ param,
    unsigned short* __restrict__ W1t, float* __restrict__ logH) {
    if (blockIdx.x < 256) {
        int idx = blockIdx.x * 256 + threadIdx.x;  // 65536
        int n = idx >> 9;
        int k = idx & 511;
        W1t[idx] = f2bf(W1[(size_t)k * DHK + n]);
    } else if (threadIdx.x < 64) {
        int t = threadIdx.x;
        int i = t >> 3, j = t & 7;
        float z = param[i * 8 + j] + param[j * 8 + i];
        logH[t] = fminf(z, 0.0f) - log1pf(expf(-fabsf(z)));
    }
}

// MFMA MLP (R7-proven: 256 thr, VGPR ~100, ~69us; do not constrain registers —
// the 512-thr variant squeezed to 36 VGPR and regressed to 103us)
__global__ __launch_bounds__(256) void mlp_mfma_kernel(
    const float* __restrict__ x, const unsigned short* __restrict__ W1t,
    const float* __restrict__ b1, const float* __restrict__ W2,
    const float* __restrict__ b2, float* __restrict__ logb0) {
    __shared__ unsigned short hs[128 * 136];
    __shared__ float W2s[128 * 8];
    __shared__ float b1s[128];
    __shared__ float b2s[8];

    const int tid = threadIdx.x;
    const int wave = tid >> 6;
    const int lane = tid & 63;
    const int q = lane >> 4;
    const int lm = lane & 15;
    const int wm = wave >> 1, wn = wave & 1;
    const int n0 = blockIdx.x * 128;

    if (tid < 128) b1s[tid] = b1[tid];
    if (tid < 8) b2s[tid] = b2[tid];
    {
        int i = tid * 4;
        *(float4*)&W2s[i] = *(const float4*)&W2[i];
    }
    __syncthreads();

    const float* xptr[4];
#pragma unroll
    for (int mt = 0; mt < 4; ++mt) {
        int r = n0 + wm * 64 + mt * 16 + lm;
        if (r > NN - 1) r = NN - 1;
        xptr[mt] = x + (size_t)r * DINK + q * 8;
    }
    const unsigned short* bptr[4];
#pragma unroll
    for (int nt = 0; nt < 4; ++nt) {
        int c = wn * 64 + nt * 16 + lm;
        bptr[nt] = W1t + (size_t)c * DINK + q * 8;
    }

    f32x4 acc[4][4];
#pragma unroll
    for (int mt = 0; mt < 4; ++mt)
#pragma unroll
        for (int nt = 0; nt < 4; ++nt) acc[mt][nt] = (f32x4){0.f, 0.f, 0.f, 0.f};

    float4 ar[4][2];
    short8 bc[4];
#pragma unroll
    for (int mt = 0; mt < 4; ++mt) {
        ar[mt][0] = *(const float4*)(xptr[mt]);
        ar[mt][1] = *(const float4*)(xptr[mt] + 4);
    }
#pragma unroll
    for (int nt = 0; nt < 4; ++nt) bc[nt] = *(const short8*)(bptr[nt]);

#pragma unroll
    for (int k0 = 32; k0 <= DINK; k0 += 32) {
        float4 ar2[4][2];
        short8 b2f[4];
        if (k0 < DINK) {
#pragma unroll
            for (int mt = 0; mt < 4; ++mt) {
                ar2[mt][0] = *(const float4*)(xptr[mt] + k0);
                ar2[mt][1] = *(const float4*)(xptr[mt] + k0 + 4);
            }
#pragma unroll
            for (int nt = 0; nt < 4; ++nt)
                b2f[nt] = *(const short8*)(bptr[nt] + k0);
        }
        short8 af[4];
#pragma unroll
        for (int mt = 0; mt < 4; ++mt) {
            union { short8 s; __hip_bfloat162 h[4]; } cv;
            cv.h[0] = __float22bfloat162_rn(make_float2(ar[mt][0].x, ar[mt][0].y));
            cv.h[1] = __float22bfloat162_rn(make_float2(ar[mt][0].z, ar[mt][0].w));
            cv.h[2] = __float22bfloat162_rn(make_float2(ar[mt][1].x, ar[mt][1].y));
            cv.h[3] = __float22bfloat162_rn(make_float2(ar[mt][1].z, ar[mt][1].w));
            af[mt] = cv.s;
        }
#pragma unroll
        for (int mt = 0; mt < 4; ++mt)
#pragma unroll
            for (int nt = 0; nt < 4; ++nt)
                acc[mt][nt] = __builtin_amdgcn_mfma_f32_16x16x32_bf16(
                    af[mt], bc[nt], acc[mt][nt], 0, 0, 0);
        if (k0 < DINK) {
#pragma unroll
            for (int mt = 0; mt < 4; ++mt) {
                ar[mt][0] = ar2[mt][0];
                ar[mt][1] = ar2[mt][1];
            }
#pragma unroll
            for (int nt = 0; nt < 4; ++nt) bc[nt] = b2f[nt];
        }
    }

#pragma unroll
    for (int nt = 0; nt < 4; ++nt) {
        int j = wn * 64 + nt * 16 + lm;
        float bj = b1s[j];
#pragma unroll
        for (int mt = 0; mt < 4; ++mt) {
            int rbase = wm * 64 + mt * 16 + q * 4;
#pragma unroll
            for (int r = 0; r < 4; ++r) {
                float h = fmaxf(acc[mt][nt][r] + bj, 0.0f);
                hs[(rbase + r) * 136 + j] = f2bf(h);
            }
        }
    }
    __syncthreads();

    int row = tid >> 1;
    int half = tid & 1;
    const unsigned short* hp = &hs[row * 136 + half * 64];
    float p[8] = {0.f, 0.f, 0.f, 0.f, 0.f, 0.f, 0.f, 0.f};
#pragma unroll
    for (int ch = 0; ch < 8; ++ch) {
        uint4 c4 = *(const uint4*)(hp + ch * 8);
        unsigned int uu[4] = {c4.x, c4.y, c4.z, c4.w};
#pragma unroll
        for (int p2 = 0; p2 < 4; ++p2) {
            float h0 = bfu2f(uu[p2] & 0xFFFFu);
            float h1 = bfu2f(uu[p2] >> 16);
            int j = half * 64 + ch * 8 + p2 * 2;
            const float* w0 = &W2s[j * 8];
            const float* w1 = &W2s[(j + 1) * 8];
#pragma unroll
            for (int c = 0; c < 8; ++c) p[c] = fmaf(h0, w0[c], p[c]);
#pragma unroll
            for (int c = 0; c < 8; ++c) p[c] = fmaf(h1, w1[c], p[c]);
        }
    }
#pragma unroll
    for (int c = 0; c < 8; ++c) p[c] += __shfl_xor(p[c], 1, 64);
    int grow = n0 + row;
    if (half == 0 && grow < NN) {
        float v[8];
        float mx = -1e30f;
#pragma unroll
        for (int c = 0; c < 8; ++c) {
            v[c] = p[c] + b2s[c];
            mx = fmaxf(mx, v[c]);
        }
        float s = 0.0f;
#pragma unroll
        for (int c = 0; c < 8; ++c) s += expf(v[c] - mx);
        float ln = mx + logf(s);
        float4* p0 = (float4*)&logb0[(size_t)grow * 8];
        p0[0] = make_float4(v[0] - ln, v[1] - ln, v[2] - ln, v[3] - ln);
        p0[1] = make_float4(v[4] - ln, v[5] - ln, v[6] - ln, v[7] - ln);
    }
}

// ---------------- CSR setup (paired: one thread per UNDIRECTED edge) --------
// Dataset structure: edge e<E2 is (s->d); its reverse is e+E2 = (d->s);
// ew[e]==ew[e+E2]; rv(e)=e+-E2. One thread places both directions and links
// their positions directly — no pos array, no rvpos pass.

__global__ __launch_bounds__(256) void deg_pair_kernel(const int* __restrict__ ei,
                                                       int* __restrict__ cnt) {
    int e = blockIdx.x * 256 + threadIdx.x;
    if (e >= E2K) return;
    int s = ei[e];
    int d = ei[EE + e];
    atomicAdd(&cnt[d], 1);  // edge e (s->d) lands on dst d
    atomicAdd(&cnt[s], 1);  // edge e+E2 (d->s) lands on dst s
}

__global__ __launch_bounds__(256) void scan_partial_kernel(
    const int* __restrict__ cnt, int* __restrict__ partial) {
    __shared__ int sd[256];
    int t = threadIdx.x;
    int i = blockIdx.x * 256 + t;
    sd[t] = (i < NN) ? cnt[i] : 0;
    __syncthreads();
#pragma unroll
    for (int s = 128; s > 0; s >>= 1) {
        if (t < s) sd[t] += sd[t + s];
        __syncthreads();
    }
    if (t == 0) partial[blockIdx.x] = sd[0];
}

__global__ __launch_bounds__(256) void scan_tops_kernel(
    const int* __restrict__ partial, int* __restrict__ tops) {
    __shared__ int sd[256];
    int t = threadIdx.x;
    sd[t] = (t < NBLKS) ? partial[t] : 0;
    __syncthreads();
#pragma unroll
    for (int s = 1; s < 256; s <<= 1) {
        int a = sd[t];
        int b = (t >= s) ? sd[t - s] : 0;
        __syncthreads();
        sd[t] = a + b;
        __syncthreads();
    }
    if (t < NBLKS) tops[t] = (t > 0) ? sd[t - 1] : 0;
}

__global__ __launch_bounds__(256) void scan_write_kernel(
    const int* __restrict__ cnt, const int* __restrict__ tops,
    int* __restrict__ off) {
    __shared__ int sd[256];
    int t = threadIdx.x;
    int i = blockIdx.x * 256 + t;
    int v = (i < NN) ? cnt[i] : 0;
    sd[t] = v;
    __syncthreads();
#pragma unroll
    for (int s = 1; s < 256; s <<= 1) {
        int a = sd[t];
        int b = (t >= s) ? sd[t - s] : 0;
        __syncthreads();
        sd[t] = a + b;
        __syncthreads();
    }
    if (i < NN) off[i] = tops[blockIdx.x] + sd[t] - v;
    if (i == NN - 1) off[NN] = EE;
}

__global__ __launch_bounds__(256) void pos_pair_kernel(
    const int* __restrict__ ei, const float* __restrict__ ew,
    const int* __restrict__ off, int* __restrict__ cnt,
    int2* __restrict__ perm_sw, int* __restrict__ perm_dst,
    int* __restrict__ perm_rvp) {
    int e = blockIdx.x * 256 + threadIdx.x;
    if (e >= E2K) return;
    int s = ei[e];
    int d = ei[EE + e];
    int wbits = __float_as_int(ew[e]);
    int pA = off[d] + atomicAdd(&cnt[d], 1);  // edge e: s->d
    int pB = off[s] + atomicAdd(&cnt[s], 1);  // edge e+E2: d->s
    int2 swA; swA.x = s; swA.y = wbits;
    int2 swB; swB.x = d; swB.y = wbits;
    perm_sw[pA] = swA;
    perm_sw[pB] = swB;
    perm_dst[pA] = d;
    perm_dst[pB] = s;
    perm_rvp[pA] = pB;
    perm_rvp[pB] = pA;
}

// ---------------- hot loop: 2 kernels/iter ----------------
// Messages deliberately UNNORMALIZED (per-edge normalizer is channel-uniform
// -> cancels in node normalize and in the xin = belief - msg chain).

__global__ __launch_bounds__(256) void edge_msg_kernel(
    const int2* __restrict__ perm_sw, const float* __restrict__ logH,
    const float* __restrict__ logb0, const float* __restrict__ xin,
    float* __restrict__ msg_out, int first) {
    __shared__ float lH[64];
    if (threadIdx.x < 64) lH[threadIdx.x] = logH[threadIdx.x];
    __syncthreads();
    int p = blockIdx.x * 256 + threadIdx.x;
    if (p >= EE) return;

    int2 sw = perm_sw[p];
    float w = __int_as_float(sw.y);
    const float4* pb = first ? (const float4*)&logb0[(size_t)sw.x * 8]
                             : (const float4*)&xin[(size_t)p * 8];
    float4 v0 = pb[0], v1 = pb[1];
    float xj[8] = {v0.x, v0.y, v0.z, v0.w, v1.x, v1.y, v1.z, v1.w};

    float M = xj[0];
#pragma unroll
    for (int c = 1; c < 8; ++c) M = fmaxf(M, xj[c]);
#pragma unroll
    for (int c = 0; c < 8; ++c) xj[c] -= M;

    float mg[8];
#pragma unroll
    for (int c2 = 0; c2 < 8; ++c2) {
        float ssum = 0.0f;
#pragma unroll
        for (int c1 = 0; c1 < 8; ++c1)
            ssum += __expf(fmaf(w, lH[c1 * 8 + c2], xj[c1]));
        mg[c2] = M + __logf(ssum);  // raw (unnormalized) message
    }

    float4* po = (float4*)&msg_out[(size_t)p * 8];
    po[0] = make_float4(mg[0], mg[1], mg[2], mg[3]);
    po[1] = make_float4(mg[4], mg[5], mg[6], mg[7]);
}

// Fused node belief + scatter. Block owns nodes [n0, n0+32) whose in-edges
// are the contiguous CSR range [off[n0], off[n0+32)) — beliefs to LDS, then
// the SAME block scatters xin[rvp[j]] = belief[dst(j)] - msg[j] (msg L1-hot).
__global__ __launch_bounds__(256) void node_fused_kernel(
    const float* __restrict__ logb0, const int* __restrict__ off,
    const float* __restrict__ msg, const int* __restrict__ perm_dst,
    const int* __restrict__ perm_rvp, float* __restrict__ xin,
    float* __restrict__ out, int last) {
    __shared__ float sb[NPB * 8];
    const int n0 = blockIdx.x * NPB;
    const int t = threadIdx.x;
    const int nl = t >> 3;
    const int c = t & 7;
    const int n = n0 + nl;

    if (n < NN) {
        int j0 = off[n], j1 = off[n + 1];
        float a = logb0[(size_t)n * 8 + c];
        for (int j = j0; j < j1; ++j) a += msg[(size_t)j * 8 + c];
        float mx = a;
#pragma unroll
        for (int s = 1; s < 8; s <<= 1) mx = fmaxf(mx, __shfl_xor(mx, s, 8));
        float sum = __expf(a - mx);
#pragma unroll
        for (int s = 1; s < 8; s <<= 1) sum += __shfl_xor(sum, s, 8);
        float v = a - (mx + __logf(sum));
        if (last) out[(size_t)n * 8 + c] = v;
        sb[nl * 8 + c] = v;
    }
    if (last) return;
    __syncthreads();

    const int nend = (n0 + NPB < NN) ? (n0 + NPB) : NN;
    const int jb0 = off[n0];
    const int jb1 = off[nend];
    const int items = (jb1 - jb0) * 8;
    for (int item = t; item < items; item += 256) {
        int j = jb0 + (item >> 3);
        int c2 = item & 7;
        int dl = perm_dst[j] - n0;
        float val = sb[dl * 8 + c2] - msg[(size_t)j * 8 + c2];
        xin[(size_t)perm_rvp[j] * 8 + c2] = val;
    }
}

extern "C" void kernel_launch(void* const* d_in, const int* in_sizes, int n_in,
                              void* d_out, int out_size, void* d_ws, size_t ws_size,
                              hipStream_t stream) {
    const float* x = (const float*)d_in[0];
    const int* ei = (const int*)d_in[1];
    const float* ew = (const float*)d_in[2];
    const float* W1 = (const float*)d_in[4];
    const float* b1 = (const float*)d_in[5];
    const float* W2 = (const float*)d_in[6];
    const float* b2 = (const float*)d_in[7];
    const float* param = (const float*)d_in[8];
    float* out = (float*)d_out;

    float* wsf = (float*)d_ws;
    float* logH = wsf;                          // 64
    float* logb0 = logH + 64;                   // 400000
    float* msg = logb0 + (size_t)NN * 8;        // 6.4M
    float* xin = msg + (size_t)EE * 8;          // 6.4M
    int* off = (int*)(xin + (size_t)EE * 8);    // 50001
    int2* perm_sw = (int2*)(off + (NN + 1));    // 800000 int2
    int* perm_rvp = (int*)(perm_sw + EE);       // 800000
    int* perm_dst = perm_rvp + EE;              // 800000
    unsigned short* W1t = (unsigned short*)(perm_dst + EE);  // 65536 bf16
    // setup-only scratch aliases xin (xin first written by node_fused it=0,
    // after all setup kernels complete)
    int* cnt = (int*)xin;                       // 50000
    int* partial = cnt + NN;                    // 196
    int* tops = partial + NBLKS;                // 196

    prep_kernel<<<257, 256, 0, stream>>>(W1, param, W1t, logH);
    mlp_mfma_kernel<<<(NN + 127) / 128, 256, 0, stream>>>(x, W1t, b1, W2, b2,
                                                          logb0);

    const int EB = (EE + 255) / 256;
    const int E2B = (E2K + 255) / 256;

    hipMemsetAsync(cnt, 0, (size_t)NN * sizeof(int), stream);
    deg_pair_kernel<<<E2B, 256, 0, stream>>>(ei, cnt);
    scan_partial_kernel<<<NBLKS, 256, 0, stream>>>(cnt, partial);
    scan_tops_kernel<<<1, 256, 0, stream>>>(partial, tops);
    scan_write_kernel<<<NBLKS, 256, 0, stream>>>(cnt, tops, off);
    hipMemsetAsync(cnt, 0, (size_t)NN * sizeof(int), stream);
    pos_pair_kernel<<<E2B, 256, 0, stream>>>(ei, ew, off, cnt, perm_sw,
                                             perm_dst, perm_rvp);

    const int NB = (NN + NPB - 1) / NPB;
    for (int it = 0; it < KIT; ++it) {
        int first = (it == 0) ? 1 : 0;
        int last = (it == KIT - 1) ? 1 : 0;
        edge_msg_kernel<<<EB, 256, 0, stream>>>(perm_sw, logH, logb0, xin, msg,
                                                first);
        node_fused_kernel<<<NB, 256, 0, stream>>>(logb0, off, msg, perm_dst,
                                                  perm_rvp, xin, out, last);
    }
}

// Round 14
// 479.497 us; speedup vs baseline: 1.1069x; 1.0036x over previous
//
#include <hip/hip_runtime.h>
#include <hip/hip_bf16.h>
#include <hip/hip_fp16.h>
#include <math.h>

#define NN 50000
#define EE 800000
#define E2K 400000
#define DINK 512
#define DHK 128
#define CK 8
#define KIT 5
#define NBLKS 196  // ceil(NN/256)
#define NPB 32     // nodes per node_fused block

typedef __attribute__((ext_vector_type(8))) short short8;
typedef __attribute__((ext_vector_type(4))) float f32x4;

__device__ __forceinline__ unsigned short f2bf(float f) {
    union { float f; unsigned int u; } v;
    v.f = f;
    unsigned int u = v.u;
    unsigned int r = (u + 0x7FFFu + ((u >> 16) & 1u)) >> 16;  // RNE
    return (unsigned short)r;
}
__device__ __forceinline__ float bfu2f(unsigned int lo16) {
    union { unsigned int u; float f; } v;
    v.u = lo16 << 16;
    return v.f;
}

// merged prep: blocks 0..255 transpose W1 -> bf16 W1t; block 256 computes logH
__global__ __launch_bounds__(256) void prep_kernel(
    const float* __restrict__ W1, const float* __restrict__ param,
    unsigned short* __restrict__ W1t, float* __restrict__ logH) {
    if (blockIdx.x < 256) {
        int idx = blockIdx.x * 256 + threadIdx.x;  // 65536
        int n = idx >> 9;
        int k = idx & 511;
        W1t[idx] = f2bf(W1[(size_t)k * DHK + n]);
    } else if (threadIdx.x < 64) {
        int t = threadIdx.x;
        int i = t >> 3, j = t & 7;
        float z = param[i * 8 + j] + param[j * 8 + i];
        logH[t] = fminf(z, 0.0f) - log1pf(expf(-fabsf(z)));
    }
}

// MFMA MLP (R7-proven: 256 thr, VGPR ~100, ~69us; do not constrain registers —
// the 512-thr variant squeezed to 36 VGPR and regressed to 103us)
__global__ __launch_bounds__(256) void mlp_mfma_kernel(
    const float* __restrict__ x, const unsigned short* __restrict__ W1t,
    const float* __restrict__ b1, const float* __restrict__ W2,
    const float* __restrict__ b2, float* __restrict__ logb0) {
    __shared__ unsigned short hs[128 * 136];
    __shared__ float W2s[128 * 8];
    __shared__ float b1s[128];
    __shared__ float b2s[8];

    const int tid = threadIdx.x;
    const int wave = tid >> 6;
    const int lane = tid & 63;
    const int q = lane >> 4;
    const int lm = lane & 15;
    const int wm = wave >> 1, wn = wave & 1;
    const int n0 = blockIdx.x * 128;

    if (tid < 128) b1s[tid] = b1[tid];
    if (tid < 8) b2s[tid] = b2[tid];
    {
        int i = tid * 4;
        *(float4*)&W2s[i] = *(const float4*)&W2[i];
    }
    __syncthreads();

    const float* xptr[4];
#pragma unroll
    for (int mt = 0; mt < 4; ++mt) {
        int r = n0 + wm * 64 + mt * 16 + lm;
        if (r > NN - 1) r = NN - 1;
        xptr[mt] = x + (size_t)r * DINK + q * 8;
    }
    const unsigned short* bptr[4];
#pragma unroll
    for (int nt = 0; nt < 4; ++nt) {
        int c = wn * 64 + nt * 16 + lm;
        bptr[nt] = W1t + (size_t)c * DINK + q * 8;
    }

    f32x4 acc[4][4];
#pragma unroll
    for (int mt = 0; mt < 4; ++mt)
#pragma unroll
        for (int nt = 0; nt < 4; ++nt) acc[mt][nt] = (f32x4){0.f, 0.f, 0.f, 0.f};

    float4 ar[4][2];
    short8 bc[4];
#pragma unroll
    for (int mt = 0; mt < 4; ++mt) {
        ar[mt][0] = *(const float4*)(xptr[mt]);
        ar[mt][1] = *(const float4*)(xptr[mt] + 4);
    }
#pragma unroll
    for (int nt = 0; nt < 4; ++nt) bc[nt] = *(const short8*)(bptr[nt]);

#pragma unroll
    for (int k0 = 32; k0 <= DINK; k0 += 32) {
        float4 ar2[4][2];
        short8 b2f[4];
        if (k0 < DINK) {
#pragma unroll
            for (int mt = 0; mt < 4; ++mt) {
                ar2[mt][0] = *(const float4*)(xptr[mt] + k0);
                ar2[mt][1] = *(const float4*)(xptr[mt] + k0 + 4);
            }
#pragma unroll
            for (int nt = 0; nt < 4; ++nt)
                b2f[nt] = *(const short8*)(bptr[nt] + k0);
        }
        short8 af[4];
#pragma unroll
        for (int mt = 0; mt < 4; ++mt) {
            union { short8 s; __hip_bfloat162 h[4]; } cv;
            cv.h[0] = __float22bfloat162_rn(make_float2(ar[mt][0].x, ar[mt][0].y));
            cv.h[1] = __float22bfloat162_rn(make_float2(ar[mt][0].z, ar[mt][0].w));
            cv.h[2] = __float22bfloat162_rn(make_float2(ar[mt][1].x, ar[mt][1].y));
            cv.h[3] = __float22bfloat162_rn(make_float2(ar[mt][1].z, ar[mt][1].w));
            af[mt] = cv.s;
        }
#pragma unroll
        for (int mt = 0; mt < 4; ++mt)
#pragma unroll
            for (int nt = 0; nt < 4; ++nt)
                acc[mt][nt] = __builtin_amdgcn_mfma_f32_16x16x32_bf16(
                    af[mt], bc[nt], acc[mt][nt], 0, 0, 0);
        if (k0 < DINK) {
#pragma unroll
            for (int mt = 0; mt < 4; ++mt) {
                ar[mt][0] = ar2[mt][0];
                ar[mt][1] = ar2[mt][1];
            }
#pragma unroll
            for (int nt = 0; nt < 4; ++nt) bc[nt] = b2f[nt];
        }
    }

#pragma unroll
    for (int nt = 0; nt < 4; ++nt) {
        int j = wn * 64 + nt * 16 + lm;
        float bj = b1s[j];
#pragma unroll
        for (int mt = 0; mt < 4; ++mt) {
            int rbase = wm * 64 + mt * 16 + q * 4;
#pragma unroll
            for (int r = 0; r < 4; ++r) {
                float h = fmaxf(acc[mt][nt][r] + bj, 0.0f);
                hs[(rbase + r) * 136 + j] = f2bf(h);
            }
        }
    }
    __syncthreads();

    int row = tid >> 1;
    int half = tid & 1;
    const unsigned short* hp = &hs[row * 136 + half * 64];
    float p[8] = {0.f, 0.f, 0.f, 0.f, 0.f, 0.f, 0.f, 0.f};
#pragma unroll
    for (int ch = 0; ch < 8; ++ch) {
        uint4 c4 = *(const uint4*)(hp + ch * 8);
        unsigned int uu[4] = {c4.x, c4.y, c4.z, c4.w};
#pragma unroll
        for (int p2 = 0; p2 < 4; ++p2) {
            float h0 = bfu2f(uu[p2] & 0xFFFFu);
            float h1 = bfu2f(uu[p2] >> 16);
            int j = half * 64 + ch * 8 + p2 * 2;
            const float* w0 = &W2s[j * 8];
            const float* w1 = &W2s[(j + 1) * 8];
#pragma unroll
            for (int c = 0; c < 8; ++c) p[c] = fmaf(h0, w0[c], p[c]);
#pragma unroll
            for (int c = 0; c < 8; ++c) p[c] = fmaf(h1, w1[c], p[c]);
        }
    }
#pragma unroll
    for (int c = 0; c < 8; ++c) p[c] += __shfl_xor(p[c], 1, 64);
    int grow = n0 + row;
    if (half == 0 && grow < NN) {
        float v[8];
        float mx = -1e30f;
#pragma unroll
        for (int c = 0; c < 8; ++c) {
            v[c] = p[c] + b2s[c];
            mx = fmaxf(mx, v[c]);
        }
        float s = 0.0f;
#pragma unroll
        for (int c = 0; c < 8; ++c) s += expf(v[c] - mx);
        float ln = mx + logf(s);
        float4* p0 = (float4*)&logb0[(size_t)grow * 8];
        p0[0] = make_float4(v[0] - ln, v[1] - ln, v[2] - ln, v[3] - ln);
        p0[1] = make_float4(v[4] - ln, v[5] - ln, v[6] - ln, v[7] - ln);
    }
}

// ---------------- CSR setup (paired: one thread per UNDIRECTED edge) --------

__global__ __launch_bounds__(256) void deg_pair_kernel(const int* __restrict__ ei,
                                                       int* __restrict__ cnt) {
    int e = blockIdx.x * 256 + threadIdx.x;
    if (e >= E2K) return;
    int s = ei[e];
    int d = ei[EE + e];
    atomicAdd(&cnt[d], 1);
    atomicAdd(&cnt[s], 1);
}

__global__ __launch_bounds__(256) void scan_partial_kernel(
    const int* __restrict__ cnt, int* __restrict__ partial) {
    __shared__ int sd[256];
    int t = threadIdx.x;
    int i = blockIdx.x * 256 + t;
    sd[t] = (i < NN) ? cnt[i] : 0;
    __syncthreads();
#pragma unroll
    for (int s = 128; s > 0; s >>= 1) {
        if (t < s) sd[t] += sd[t + s];
        __syncthreads();
    }
    if (t == 0) partial[blockIdx.x] = sd[0];
}

__global__ __launch_bounds__(256) void scan_tops_kernel(
    const int* __restrict__ partial, int* __restrict__ tops) {
    __shared__ int sd[256];
    int t = threadIdx.x;
    sd[t] = (t < NBLKS) ? partial[t] : 0;
    __syncthreads();
#pragma unroll
    for (int s = 1; s < 256; s <<= 1) {
        int a = sd[t];
        int b = (t >= s) ? sd[t - s] : 0;
        __syncthreads();
        sd[t] = a + b;
        __syncthreads();
    }
    if (t < NBLKS) tops[t] = (t > 0) ? sd[t - 1] : 0;
}

__global__ __launch_bounds__(256) void scan_write_kernel(
    const int* __restrict__ cnt, const int* __restrict__ tops,
    int* __restrict__ off) {
    __shared__ int sd[256];
    int t = threadIdx.x;
    int i = blockIdx.x * 256 + t;
    int v = (i < NN) ? cnt[i] : 0;
    sd[t] = v;
    __syncthreads();
#pragma unroll
    for (int s = 1; s < 256; s <<= 1) {
        int a = sd[t];
        int b = (t >= s) ? sd[t - s] : 0;
        __syncthreads();
        sd[t] = a + b;
        __syncthreads();
    }
    if (i < NN) off[i] = tops[blockIdx.x] + sd[t] - v;
    if (i == NN - 1) off[NN] = EE;
}

__global__ __launch_bounds__(256) void pos_pair_kernel(
    const int* __restrict__ ei, const float* __restrict__ ew,
    const int* __restrict__ off, int* __restrict__ cnt,
    int* __restrict__ perm_src, float* __restrict__ perm_w,
    int* __restrict__ perm_dst, int* __restrict__ perm_rvp) {
    int e = blockIdx.x * 256 + threadIdx.x;
    if (e >= E2K) return;
    int s = ei[e];
    int d = ei[EE + e];
    float w = ew[e];
    int pA = off[d] + atomicAdd(&cnt[d], 1);  // edge e: s->d
    int pB = off[s] + atomicAdd(&cnt[s], 1);  // edge e+E2: d->s
    perm_src[pA] = s;
    perm_src[pB] = d;
    perm_w[pA] = w;
    perm_w[pB] = w;
    perm_dst[pA] = d;
    perm_dst[pB] = s;
    perm_rvp[pA] = pB;
    perm_rvp[pB] = pA;
}

// ---------------- hot loop: 2 kernels/iter, fp16 msg/xin storage ------------
// Messages NORMALIZED per edge (keeps values small so fp16 ulp stays tiny).

__global__ __launch_bounds__(256) void edge_msg_kernel(
    const int* __restrict__ perm_src, const float* __restrict__ perm_w,
    const float* __restrict__ logH, const float* __restrict__ logb0,
    const uint4* __restrict__ xin16, uint4* __restrict__ msg16, int first) {
    __shared__ float lH[64];
    if (threadIdx.x < 64) lH[threadIdx.x] = logH[threadIdx.x];
    __syncthreads();
    int p = blockIdx.x * 256 + threadIdx.x;
    if (p >= EE) return;

    float w = perm_w[p];
    float xj[8];
    if (first) {
        int s = perm_src[p];
        const float4* pb = (const float4*)&logb0[(size_t)s * 8];
        float4 v0 = pb[0], v1 = pb[1];
        xj[0] = v0.x; xj[1] = v0.y; xj[2] = v0.z; xj[3] = v0.w;
        xj[4] = v1.x; xj[5] = v1.y; xj[6] = v1.z; xj[7] = v1.w;
    } else {
        union { uint4 u; _Float16 h[8]; } cv;
        cv.u = xin16[p];
#pragma unroll
        for (int c = 0; c < 8; ++c) xj[c] = (float)cv.h[c];
    }

    float M = xj[0];
#pragma unroll
    for (int c = 1; c < 8; ++c) M = fmaxf(M, xj[c]);
#pragma unroll
    for (int c = 0; c < 8; ++c) xj[c] -= M;

    float mg[8];
#pragma unroll
    for (int c2 = 0; c2 < 8; ++c2) {
        float ssum = 0.0f;
#pragma unroll
        for (int c1 = 0; c1 < 8; ++c1)
            ssum += __expf(fmaf(w, lH[c1 * 8 + c2], xj[c1]));
        mg[c2] = __logf(ssum);
    }
    // normalize message (keeps fp16 values small; exact no-op in the algebra)
    float mm = mg[0];
#pragma unroll
    for (int c = 1; c < 8; ++c) mm = fmaxf(mm, mg[c]);
    float se = 0.0f;
#pragma unroll
    for (int c = 0; c < 8; ++c) se += __expf(mg[c] - mm);
    float ln = mm + __logf(se);

    union { uint4 u; _Float16 h[8]; } ov;
#pragma unroll
    for (int c = 0; c < 8; ++c) ov.h[c] = (_Float16)(mg[c] - ln);
    msg16[p] = ov.u;
}

// Fused node belief + scatter. Block owns nodes [n0, n0+32) whose in-edges
// are the contiguous CSR range [off[n0], off[n0+32)) — beliefs to LDS, then
// the SAME block scatters xin[rvp[j]] = belief[dst(j)] - msg[j] (msg L1-hot).
__global__ __launch_bounds__(256) void node_fused_kernel(
    const float* __restrict__ logb0, const int* __restrict__ off,
    const uint4* __restrict__ msg16, const int* __restrict__ perm_dst,
    const int* __restrict__ perm_rvp, uint4* __restrict__ xin16,
    float* __restrict__ out, int last) {
    __shared__ float sb[NPB * 8];
    const int n0 = blockIdx.x * NPB;
    const int t = threadIdx.x;
    const int nl = t >> 3;
    const int c = t & 7;
    const int n = n0 + nl;
    const _Float16* msgh = (const _Float16*)msg16;

    if (n < NN) {
        int j0 = off[n], j1 = off[n + 1];
        float a = logb0[(size_t)n * 8 + c];
        for (int j = j0; j < j1; ++j) a += (float)msgh[(size_t)j * 8 + c];
        float mx = a;
#pragma unroll
        for (int s = 1; s < 8; s <<= 1) mx = fmaxf(mx, __shfl_xor(mx, s, 8));
        float sum = __expf(a - mx);
#pragma unroll
        for (int s = 1; s < 8; s <<= 1) sum += __shfl_xor(sum, s, 8);
        float v = a - (mx + __logf(sum));
        if (last) out[(size_t)n * 8 + c] = v;
        sb[nl * 8 + c] = v;
    }
    if (last) return;
    __syncthreads();

    _Float16* xinh = (_Float16*)xin16;
    const int nend = (n0 + NPB < NN) ? (n0 + NPB) : NN;
    const int jb0 = off[n0];
    const int jb1 = off[nend];
    const int items = (jb1 - jb0) * 8;
    for (int item = t; item < items; item += 256) {
        int j = jb0 + (item >> 3);
        int c2 = item & 7;
        int dl = perm_dst[j] - n0;
        float val = sb[dl * 8 + c2] - (float)msgh[(size_t)j * 8 + c2];
        xinh[(size_t)perm_rvp[j] * 8 + c2] = (_Float16)val;
    }
}

extern "C" void kernel_launch(void* const* d_in, const int* in_sizes, int n_in,
                              void* d_out, int out_size, void* d_ws, size_t ws_size,
                              hipStream_t stream) {
    const float* x = (const float*)d_in[0];
    const int* ei = (const int*)d_in[1];
    const float* ew = (const float*)d_in[2];
    const float* W1 = (const float*)d_in[4];
    const float* b1 = (const float*)d_in[5];
    const float* W2 = (const float*)d_in[6];
    const float* b2 = (const float*)d_in[7];
    const float* param = (const float*)d_in[8];
    float* out = (float*)d_out;

    float* wsf = (float*)d_ws;
    float* logH = wsf;                          // 64
    float* logb0 = logH + 64;                   // 400000
    uint4* msg16 = (uint4*)(logb0 + (size_t)NN * 8);  // EE*16B = 12.8MB
    uint4* xin16 = msg16 + EE;                  // 12.8MB
    int* off = (int*)(xin16 + EE);              // 50001
    int* perm_src = off + (NN + 1);             // 800000
    float* perm_w = (float*)(perm_src + EE);    // 800000
    int* perm_rvp = (int*)(perm_w + EE);        // 800000
    int* perm_dst = perm_rvp + EE;              // 800000
    unsigned short* W1t = (unsigned short*)(perm_dst + EE);  // 65536 bf16
    // setup-only scratch aliases xin16 (first written by node_fused it=0)
    int* cnt = (int*)xin16;                     // 50000
    int* partial = cnt + NN;                    // 196
    int* tops = partial + NBLKS;                // 196

    prep_kernel<<<257, 256, 0, stream>>>(W1, param, W1t, logH);
    mlp_mfma_kernel<<<(NN + 127) / 128, 256, 0, stream>>>(x, W1t, b1, W2, b2,
                                                          logb0);

    const int EB = (EE + 255) / 256;
    const int E2B = (E2K + 255) / 256;

    hipMemsetAsync(cnt, 0, (size_t)NN * sizeof(int), stream);
    deg_pair_kernel<<<E2B, 256, 0, stream>>>(ei, cnt);
    scan_partial_kernel<<<NBLKS, 256, 0, stream>>>(cnt, partial);
    scan_tops_kernel<<<1, 256, 0, stream>>>(partial, tops);
    scan_write_kernel<<<NBLKS, 256, 0, stream>>>(cnt, tops, off);
    hipMemsetAsync(cnt, 0, (size_t)NN * sizeof(int), stream);
    pos_pair_kernel<<<E2B, 256, 0, stream>>>(ei, ew, off, cnt, perm_src,
                                             perm_w, perm_dst, perm_rvp);

    const int NB = (NN + NPB - 1) / NPB;
    for (int it = 0; it < KIT; ++it) {
        int first = (it == 0) ? 1 : 0;
        int last = (it == KIT - 1) ? 1 : 0;
        edge_msg_kernel<<<EB, 256, 0, stream>>>(perm_src, perm_w, logH, logb0,
                                                xin16, msg16, first);
        node_fused_kernel<<<NB, 256, 0, stream>>>(logb0, off, msg16, perm_dst,
                                                  perm_rvp, xin16, out, last);
    }
}

// Round 15
// 432.228 us; speedup vs baseline: 1.2280x; 1.1094x over previous
//
#include <hip/hip_runtime.h>
#include <hip/hip_bf16.h>
#include <hip/hip_fp16.h>
#include <math.h>

#define NN 50000
#define EE 800000
#define E2K 400000
#define DINK 512
#define DHK 128
#define CK 8
#define KIT 5
#define NBLKS 196  // ceil(NN/256)
#define NPB 32     // nodes per bp_iter block
#define CAP 1024   // LDS message cache (edges); block edge-count mean ~512

typedef __attribute__((ext_vector_type(8))) short short8;
typedef __attribute__((ext_vector_type(4))) float f32x4;

__device__ __forceinline__ unsigned short f2bf(float f) {
    union { float f; unsigned int u; } v;
    v.f = f;
    unsigned int u = v.u;
    unsigned int r = (u + 0x7FFFu + ((u >> 16) & 1u)) >> 16;  // RNE
    return (unsigned short)r;
}
__device__ __forceinline__ float bfu2f(unsigned int lo16) {
    union { unsigned int u; float f; } v;
    v.u = lo16 << 16;
    return v.f;
}

// merged prep: blocks 0..255 transpose W1 -> bf16 W1t; block 256 computes logH
__global__ __launch_bounds__(256) void prep_kernel(
    const float* __restrict__ W1, const float* __restrict__ param,
    unsigned short* __restrict__ W1t, float* __restrict__ logH) {
    if (blockIdx.x < 256) {
        int idx = blockIdx.x * 256 + threadIdx.x;  // 65536
        int n = idx >> 9;
        int k = idx & 511;
        W1t[idx] = f2bf(W1[(size_t)k * DHK + n]);
    } else if (threadIdx.x < 64) {
        int t = threadIdx.x;
        int i = t >> 3, j = t & 7;
        float z = param[i * 8 + j] + param[j * 8 + i];
        logH[t] = fminf(z, 0.0f) - log1pf(expf(-fabsf(z)));
    }
}

// MFMA MLP (R7-proven: 256 thr, VGPR ~100, ~69us; do not constrain registers —
// the 512-thr variant squeezed to 36 VGPR and regressed to 103us)
__global__ __launch_bounds__(256) void mlp_mfma_kernel(
    const float* __restrict__ x, const unsigned short* __restrict__ W1t,
    const float* __restrict__ b1, const float* __restrict__ W2,
    const float* __restrict__ b2, float* __restrict__ logb0) {
    __shared__ unsigned short hs[128 * 136];
    __shared__ float W2s[128 * 8];
    __shared__ float b1s[128];
    __shared__ float b2s[8];

    const int tid = threadIdx.x;
    const int wave = tid >> 6;
    const int lane = tid & 63;
    const int q = lane >> 4;
    const int lm = lane & 15;
    const int wm = wave >> 1, wn = wave & 1;
    const int n0 = blockIdx.x * 128;

    if (tid < 128) b1s[tid] = b1[tid];
    if (tid < 8) b2s[tid] = b2[tid];
    {
        int i = tid * 4;
        *(float4*)&W2s[i] = *(const float4*)&W2[i];
    }
    __syncthreads();

    const float* xptr[4];
#pragma unroll
    for (int mt = 0; mt < 4; ++mt) {
        int r = n0 + wm * 64 + mt * 16 + lm;
        if (r > NN - 1) r = NN - 1;
        xptr[mt] = x + (size_t)r * DINK + q * 8;
    }
    const unsigned short* bptr[4];
#pragma unroll
    for (int nt = 0; nt < 4; ++nt) {
        int c = wn * 64 + nt * 16 + lm;
        bptr[nt] = W1t + (size_t)c * DINK + q * 8;
    }

    f32x4 acc[4][4];
#pragma unroll
    for (int mt = 0; mt < 4; ++mt)
#pragma unroll
        for (int nt = 0; nt < 4; ++nt) acc[mt][nt] = (f32x4){0.f, 0.f, 0.f, 0.f};

    float4 ar[4][2];
    short8 bc[4];
#pragma unroll
    for (int mt = 0; mt < 4; ++mt) {
        ar[mt][0] = *(const float4*)(xptr[mt]);
        ar[mt][1] = *(const float4*)(xptr[mt] + 4);
    }
#pragma unroll
    for (int nt = 0; nt < 4; ++nt) bc[nt] = *(const short8*)(bptr[nt]);

#pragma unroll
    for (int k0 = 32; k0 <= DINK; k0 += 32) {
        float4 ar2[4][2];
        short8 b2f[4];
        if (k0 < DINK) {
#pragma unroll
            for (int mt = 0; mt < 4; ++mt) {
                ar2[mt][0] = *(const float4*)(xptr[mt] + k0);
                ar2[mt][1] = *(const float4*)(xptr[mt] + k0 + 4);
            }
#pragma unroll
            for (int nt = 0; nt < 4; ++nt)
                b2f[nt] = *(const short8*)(bptr[nt] + k0);
        }
        short8 af[4];
#pragma unroll
        for (int mt = 0; mt < 4; ++mt) {
            union { short8 s; __hip_bfloat162 h[4]; } cv;
            cv.h[0] = __float22bfloat162_rn(make_float2(ar[mt][0].x, ar[mt][0].y));
            cv.h[1] = __float22bfloat162_rn(make_float2(ar[mt][0].z, ar[mt][0].w));
            cv.h[2] = __float22bfloat162_rn(make_float2(ar[mt][1].x, ar[mt][1].y));
            cv.h[3] = __float22bfloat162_rn(make_float2(ar[mt][1].z, ar[mt][1].w));
            af[mt] = cv.s;
        }
#pragma unroll
        for (int mt = 0; mt < 4; ++mt)
#pragma unroll
            for (int nt = 0; nt < 4; ++nt)
                acc[mt][nt] = __builtin_amdgcn_mfma_f32_16x16x32_bf16(
                    af[mt], bc[nt], acc[mt][nt], 0, 0, 0);
        if (k0 < DINK) {
#pragma unroll
            for (int mt = 0; mt < 4; ++mt) {
                ar[mt][0] = ar2[mt][0];
                ar[mt][1] = ar2[mt][1];
            }
#pragma unroll
            for (int nt = 0; nt < 4; ++nt) bc[nt] = b2f[nt];
        }
    }

#pragma unroll
    for (int nt = 0; nt < 4; ++nt) {
        int j = wn * 64 + nt * 16 + lm;
        float bj = b1s[j];
#pragma unroll
        for (int mt = 0; mt < 4; ++mt) {
            int rbase = wm * 64 + mt * 16 + q * 4;
#pragma unroll
            for (int r = 0; r < 4; ++r) {
                float h = fmaxf(acc[mt][nt][r] + bj, 0.0f);
                hs[(rbase + r) * 136 + j] = f2bf(h);
            }
        }
    }
    __syncthreads();

    int row = tid >> 1;
    int half = tid & 1;
    const unsigned short* hp = &hs[row * 136 + half * 64];
    float p[8] = {0.f, 0.f, 0.f, 0.f, 0.f, 0.f, 0.f, 0.f};
#pragma unroll
    for (int ch = 0; ch < 8; ++ch) {
        uint4 c4 = *(const uint4*)(hp + ch * 8);
        unsigned int uu[4] = {c4.x, c4.y, c4.z, c4.w};
#pragma unroll
        for (int p2 = 0; p2 < 4; ++p2) {
            float h0 = bfu2f(uu[p2] & 0xFFFFu);
            float h1 = bfu2f(uu[p2] >> 16);
            int j = half * 64 + ch * 8 + p2 * 2;
            const float* w0 = &W2s[j * 8];
            const float* w1 = &W2s[(j + 1) * 8];
#pragma unroll
            for (int c = 0; c < 8; ++c) p[c] = fmaf(h0, w0[c], p[c]);
#pragma unroll
            for (int c = 0; c < 8; ++c) p[c] = fmaf(h1, w1[c], p[c]);
        }
    }
#pragma unroll
    for (int c = 0; c < 8; ++c) p[c] += __shfl_xor(p[c], 1, 64);
    int grow = n0 + row;
    if (half == 0 && grow < NN) {
        float v[8];
        float mx = -1e30f;
#pragma unroll
        for (int c = 0; c < 8; ++c) {
            v[c] = p[c] + b2s[c];
            mx = fmaxf(mx, v[c]);
        }
        float s = 0.0f;
#pragma unroll
        for (int c = 0; c < 8; ++c) s += expf(v[c] - mx);
        float ln = mx + logf(s);
        float4* p0 = (float4*)&logb0[(size_t)grow * 8];
        p0[0] = make_float4(v[0] - ln, v[1] - ln, v[2] - ln, v[3] - ln);
        p0[1] = make_float4(v[4] - ln, v[5] - ln, v[6] - ln, v[7] - ln);
    }
}

// ---------------- CSR setup (paired: one thread per UNDIRECTED edge) --------

__global__ __launch_bounds__(256) void deg_pair_kernel(const int* __restrict__ ei,
                                                       int* __restrict__ cnt) {
    int e = blockIdx.x * 256 + threadIdx.x;
    if (e >= E2K) return;
    int s = ei[e];
    int d = ei[EE + e];
    atomicAdd(&cnt[d], 1);
    atomicAdd(&cnt[s], 1);
}

__global__ __launch_bounds__(256) void scan_partial_kernel(
    const int* __restrict__ cnt, int* __restrict__ partial) {
    __shared__ int sd[256];
    int t = threadIdx.x;
    int i = blockIdx.x * 256 + t;
    sd[t] = (i < NN) ? cnt[i] : 0;
    __syncthreads();
#pragma unroll
    for (int s = 128; s > 0; s >>= 1) {
        if (t < s) sd[t] += sd[t + s];
        __syncthreads();
    }
    if (t == 0) partial[blockIdx.x] = sd[0];
}

__global__ __launch_bounds__(256) void scan_tops_kernel(
    const int* __restrict__ partial, int* __restrict__ tops) {
    __shared__ int sd[256];
    int t = threadIdx.x;
    sd[t] = (t < NBLKS) ? partial[t] : 0;
    __syncthreads();
#pragma unroll
    for (int s = 1; s < 256; s <<= 1) {
        int a = sd[t];
        int b = (t >= s) ? sd[t - s] : 0;
        __syncthreads();
        sd[t] = a + b;
        __syncthreads();
    }
    if (t < NBLKS) tops[t] = (t > 0) ? sd[t - 1] : 0;
}

__global__ __launch_bounds__(256) void scan_write_kernel(
    const int* __restrict__ cnt, const int* __restrict__ tops,
    int* __restrict__ off) {
    __shared__ int sd[256];
    int t = threadIdx.x;
    int i = blockIdx.x * 256 + t;
    int v = (i < NN) ? cnt[i] : 0;
    sd[t] = v;
    __syncthreads();
#pragma unroll
    for (int s = 1; s < 256; s <<= 1) {
        int a = sd[t];
        int b = (t >= s) ? sd[t - s] : 0;
        __syncthreads();
        sd[t] = a + b;
        __syncthreads();
    }
    if (i < NN) off[i] = tops[blockIdx.x] + sd[t] - v;
    if (i == NN - 1) off[NN] = EE;
}

// packed stores: perm_sw=(src,wbits), perm_dr=(dst,rvp) — 4 random 8B stores
// per undirected edge (was 8 random 4B stores)
__global__ __launch_bounds__(256) void pos_pair_kernel(
    const int* __restrict__ ei, const float* __restrict__ ew,
    const int* __restrict__ off, int* __restrict__ cnt,
    int2* __restrict__ perm_sw, int2* __restrict__ perm_dr) {
    int e = blockIdx.x * 256 + threadIdx.x;
    if (e >= E2K) return;
    int s = ei[e];
    int d = ei[EE + e];
    int wbits = __float_as_int(ew[e]);
    int pA = off[d] + atomicAdd(&cnt[d], 1);  // edge e: s->d
    int pB = off[s] + atomicAdd(&cnt[s], 1);  // edge e+E2: d->s
    int2 v;
    v.x = s; v.y = wbits; perm_sw[pA] = v;
    v.x = d;              perm_sw[pB] = v;
    v.x = d; v.y = pB;    perm_dr[pA] = v;
    v.x = s; v.y = pA;    perm_dr[pB] = v;
}

// ---------------- fused BP iteration: ONE dispatch per iteration ------------
// Block owns nodes [n0,n0+NPB) and their contiguous CSR edge range
// [off[n0], off[n0+NPB)). Messages are computed edge-parallel into LDS
// (never global), aggregated per-node, normalized, then scattered as
// xin_next[rvp[j]] = belief[dst(j)] - mg[j]. Messages normalized per edge
// (channel-uniform shift cancels; keeps fp16 ulp small).
__global__ __launch_bounds__(256) void bp_iter_kernel(
    const float* __restrict__ logb0, const int* __restrict__ off,
    const int2* __restrict__ perm_sw, const int2* __restrict__ perm_dr,
    const float* __restrict__ logH, const uint4* __restrict__ xin_cur,
    uint4* __restrict__ xin_next, float* __restrict__ out,
    int first, int last) {
    __shared__ _Float16 smg[CAP * 8];  // 16 KB message cache
    __shared__ float sb[NPB * 8];
    __shared__ float lH[64];
    const int t = threadIdx.x;
    if (t < 64) lH[t] = logH[t];

    const int n0 = blockIdx.x * NPB;
    const int nend = (n0 + NPB < NN) ? (n0 + NPB) : NN;
    const int jb0 = off[n0];
    const int jb1 = off[nend];
    const int nl = t >> 3;
    const int c = t & 7;
    const int n = n0 + nl;

    float a = 0.0f;
    int jn0 = 0, jn1 = 0;
    if (n < nend) {
        jn0 = off[n];
        jn1 = off[n + 1];
        a = logb0[(size_t)n * 8 + c];
    }
    __syncthreads();  // lH ready

    const int single = (jb1 - jb0) <= CAP;

    // ---- message compute + aggregation (chunked; single chunk typical) ----
    for (int cb = jb0; cb < jb1; cb += CAP) {
        int ce = (cb + CAP < jb1) ? (cb + CAP) : jb1;
        for (int j = cb + t; j < ce; j += 256) {
            int2 sw = perm_sw[j];
            float w = __int_as_float(sw.y);
            float xj[8];
            if (first) {
                const float4* pb = (const float4*)&logb0[(size_t)sw.x * 8];
                float4 v0 = pb[0], v1 = pb[1];
                xj[0] = v0.x; xj[1] = v0.y; xj[2] = v0.z; xj[3] = v0.w;
                xj[4] = v1.x; xj[5] = v1.y; xj[6] = v1.z; xj[7] = v1.w;
            } else {
                union { uint4 u; _Float16 h[8]; } cv;
                cv.u = xin_cur[j];
#pragma unroll
                for (int k = 0; k < 8; ++k) xj[k] = (float)cv.h[k];
            }
            float M = xj[0];
#pragma unroll
            for (int k = 1; k < 8; ++k) M = fmaxf(M, xj[k]);
#pragma unroll
            for (int k = 0; k < 8; ++k) xj[k] -= M;
            float mg[8];
#pragma unroll
            for (int c2 = 0; c2 < 8; ++c2) {
                float ssum = 0.0f;
#pragma unroll
                for (int c1 = 0; c1 < 8; ++c1)
                    ssum += __expf(fmaf(w, lH[c1 * 8 + c2], xj[c1]));
                mg[c2] = __logf(ssum);
            }
            float mm = mg[0];
#pragma unroll
            for (int k = 1; k < 8; ++k) mm = fmaxf(mm, mg[k]);
            float se = 0.0f;
#pragma unroll
            for (int k = 0; k < 8; ++k) se += __expf(mg[k] - mm);
            float ln = mm + __logf(se);
            union { uint4 u; _Float16 h[8]; } ov;
#pragma unroll
            for (int k = 0; k < 8; ++k) ov.h[k] = (_Float16)(mg[k] - ln);
            *(uint4*)&smg[(j - cb) * 8] = ov.u;
        }
        __syncthreads();
        // aggregate this chunk's contribution for my node
        int lo = (jn0 > cb) ? jn0 : cb;
        int hi = (jn1 < ce) ? jn1 : ce;
        for (int j = lo; j < hi; ++j) a += (float)smg[(j - cb) * 8 + c];
        __syncthreads();  // protect smg before next chunk / reuse below
    }

    // ---- normalize belief (8-thread groups) ----
    float mx = a;
#pragma unroll
    for (int s = 1; s < 8; s <<= 1) mx = fmaxf(mx, __shfl_xor(mx, s, 8));
    float sum = __expf(a - mx);
#pragma unroll
    for (int s = 1; s < 8; s <<= 1) sum += __shfl_xor(sum, s, 8);
    float v = a - (mx + __logf(sum));
    if (n < nend) {
        if (last) out[(size_t)n * 8 + c] = v;
        sb[nl * 8 + c] = v;
    }
    if (last) return;
    __syncthreads();

    // ---- scatter next-iter inputs ----
    for (int cb = jb0; cb < jb1; cb += CAP) {
        int ce = (cb + CAP < jb1) ? (cb + CAP) : jb1;
        if (!single) {
            // recompute this chunk's messages into smg (rare path)
            for (int j = cb + t; j < ce; j += 256) {
                int2 sw = perm_sw[j];
                float w = __int_as_float(sw.y);
                float xj[8];
                if (first) {
                    const float4* pb = (const float4*)&logb0[(size_t)sw.x * 8];
                    float4 v0 = pb[0], v1 = pb[1];
                    xj[0] = v0.x; xj[1] = v0.y; xj[2] = v0.z; xj[3] = v0.w;
                    xj[4] = v1.x; xj[5] = v1.y; xj[6] = v1.z; xj[7] = v1.w;
                } else {
                    union { uint4 u; _Float16 h[8]; } cv;
                    cv.u = xin_cur[j];
#pragma unroll
                    for (int k = 0; k < 8; ++k) xj[k] = (float)cv.h[k];
                }
                float M = xj[0];
#pragma unroll
                for (int k = 1; k < 8; ++k) M = fmaxf(M, xj[k]);
#pragma unroll
                for (int k = 0; k < 8; ++k) xj[k] -= M;
                float mg[8];
#pragma unroll
                for (int c2 = 0; c2 < 8; ++c2) {
                    float ssum = 0.0f;
#pragma unroll
                    for (int c1 = 0; c1 < 8; ++c1)
                        ssum += __expf(fmaf(w, lH[c1 * 8 + c2], xj[c1]));
                    mg[c2] = __logf(ssum);
                }
                float mm = mg[0];
#pragma unroll
                for (int k = 1; k < 8; ++k) mm = fmaxf(mm, mg[k]);
                float se = 0.0f;
#pragma unroll
                for (int k = 0; k < 8; ++k) se += __expf(mg[k] - mm);
                float ln = mm + __logf(se);
                union { uint4 u; _Float16 h[8]; } ov;
#pragma unroll
                for (int k = 0; k < 8; ++k) ov.h[k] = (_Float16)(mg[k] - ln);
                *(uint4*)&smg[(j - cb) * 8] = ov.u;
            }
            __syncthreads();
        }
        _Float16* xinh = (_Float16*)xin_next;
        int items = (ce - cb) * 8;
        for (int item = t; item < items; item += 256) {
            int j = cb + (item >> 3);
            int c2 = item & 7;
            int2 dr = perm_dr[j];
            int dl = dr.x - n0;
            float val = sb[dl * 8 + c2] - (float)smg[(j - cb) * 8 + c2];
            xinh[(size_t)dr.y * 8 + c2] = (_Float16)val;
        }
        if (!single) __syncthreads();
    }
}

extern "C" void kernel_launch(void* const* d_in, const int* in_sizes, int n_in,
                              void* d_out, int out_size, void* d_ws, size_t ws_size,
                              hipStream_t stream) {
    const float* x = (const float*)d_in[0];
    const int* ei = (const int*)d_in[1];
    const float* ew = (const float*)d_in[2];
    const float* W1 = (const float*)d_in[4];
    const float* b1 = (const float*)d_in[5];
    const float* W2 = (const float*)d_in[6];
    const float* b2 = (const float*)d_in[7];
    const float* param = (const float*)d_in[8];
    float* out = (float*)d_out;

    float* wsf = (float*)d_ws;
    float* logH = wsf;                          // 64
    float* logb0 = logH + 64;                   // 400000
    uint4* xinA = (uint4*)(logb0 + (size_t)NN * 8);  // 12.8MB
    uint4* xinB = xinA + EE;                    // 12.8MB
    int* off = (int*)(xinB + EE);               // 50001
    int2* perm_sw = (int2*)(off + (NN + 1));    // 800000 int2
    int2* perm_dr = perm_sw + EE;               // 800000 int2
    unsigned short* W1t = (unsigned short*)(perm_dr + EE);  // 65536 bf16
    // setup-only scratch aliases xinA (first written at iter 2, after setup)
    int* cnt = (int*)xinA;                      // 50000
    int* partial = cnt + NN;                    // 196
    int* tops = partial + NBLKS;                // 196

    prep_kernel<<<257, 256, 0, stream>>>(W1, param, W1t, logH);
    mlp_mfma_kernel<<<(NN + 127) / 128, 256, 0, stream>>>(x, W1t, b1, W2, b2,
                                                          logb0);

    const int E2B = (E2K + 255) / 256;

    hipMemsetAsync(cnt, 0, (size_t)NN * sizeof(int), stream);
    deg_pair_kernel<<<E2B, 256, 0, stream>>>(ei, cnt);
    scan_partial_kernel<<<NBLKS, 256, 0, stream>>>(cnt, partial);
    scan_tops_kernel<<<1, 256, 0, stream>>>(partial, tops);
    scan_write_kernel<<<NBLKS, 256, 0, stream>>>(cnt, tops, off);
    hipMemsetAsync(cnt, 0, (size_t)NN * sizeof(int), stream);
    pos_pair_kernel<<<E2B, 256, 0, stream>>>(ei, ew, off, cnt, perm_sw, perm_dr);

    const int NB = (NN + NPB - 1) / NPB;
    uint4* cur = xinA;  // unused on first iter (reads logb0)
    uint4* nxt = xinB;
    for (int it = 0; it < KIT; ++it) {
        bp_iter_kernel<<<NB, 256, 0, stream>>>(
            logb0, off, perm_sw, perm_dr, logH, cur, nxt, out,
            it == 0 ? 1 : 0, it == KIT - 1 ? 1 : 0);
        uint4* tmp = cur; cur = nxt; nxt = tmp;
    }
}